// Round 1
// baseline (2082.564 us; speedup 1.0000x reference)
//
#include <hip/hip_runtime.h>
#include <math.h>

#define BB 2
#define SS 2048
#define DIMM 1024
#define NHH 8
#define DHH 128

constexpr float GATE_CAP = 15.0f;
constexpr float B_EPS = 5e-5f;
constexpr float N_EPS = 1e-6f;

#define TM 32
#define TS 32
#define LDP 132   // padded f32 stride for 128-wide tiles (breaks bank conflicts)
#define WP 36     // padded stride for 32-wide w tile, 16B-aligned rows

// ---------------- Kernel 1: gate preactivations ----------------
// pre[o] = sum_j ifgate_w[o][j] * concat(q,k,v)[bs][j] + b[o]; softcap; split i/f.
__global__ __launch_bounds__(256) void gate_kernel(
    const float* __restrict__ q, const float* __restrict__ k, const float* __restrict__ v,
    const float* __restrict__ gw, const float* __restrict__ gb,
    float* __restrict__ i_pre, float* __restrict__ lfcs)
{
    const int tid = threadIdx.x;
    const int bs0 = blockIdx.x * 4;

    float acc[4][16];
    #pragma unroll
    for (int rr = 0; rr < 4; rr++)
        #pragma unroll
        for (int o = 0; o < 16; o++) acc[rr][o] = 0.f;

    for (int j = tid; j < 3 * DIMM; j += 256) {
        float x[4];
        #pragma unroll
        for (int rr = 0; rr < 4; rr++) {
            const int bs = bs0 + rr;
            float xv;
            if (j < DIMM)            xv = q[(size_t)bs * DIMM + j];
            else if (j < 2 * DIMM)   xv = k[(size_t)bs * DIMM + (j - DIMM)];
            else                     xv = v[(size_t)bs * DIMM + (j - 2 * DIMM)];
            x[rr] = xv;
        }
        #pragma unroll
        for (int o = 0; o < 16; o++) {
            const float wv = gw[o * 3 * DIMM + j];
            #pragma unroll
            for (int rr = 0; rr < 4; rr++) acc[rr][o] += wv * x[rr];
        }
    }

    __shared__ float red[4][4][16]; // [wave][rr][o]
    const int lane = tid & 63, wave = tid >> 6;
    #pragma unroll
    for (int rr = 0; rr < 4; rr++) {
        #pragma unroll
        for (int o = 0; o < 16; o++) {
            float s = acc[rr][o];
            s += __shfl_xor(s, 32); s += __shfl_xor(s, 16); s += __shfl_xor(s, 8);
            s += __shfl_xor(s, 4);  s += __shfl_xor(s, 2);  s += __shfl_xor(s, 1);
            if (lane == 0) red[wave][rr][o] = s;
        }
    }
    __syncthreads();
    if (tid < 64) {
        const int rr = tid >> 4, o = tid & 15;
        float p = red[0][rr][o] + red[1][rr][o] + red[2][rr][o] + red[3][rr][o] + gb[o];
        p = GATE_CAP * tanhf(p / GATE_CAP);
        const int bs = bs0 + rr;
        const int b = bs / SS, s = bs % SS;
        if (o < NHH) {
            i_pre[((size_t)b * NHH + o) * SS + s] = p;
        } else {
            const int h = o - NHH;
            // log_sigmoid(p)
            const float ls = (p >= 0.f) ? -log1pf(expf(-p)) : p - log1pf(expf(p));
            lfcs[((size_t)b * NHH + h) * SS + s] = ls;   // log_fg; becomes cumsum in scan
        }
    }
}

// ---------------- Kernel 2: serial cumsum + prefix-max (16 chains) ----------------
__global__ void scan_kernel(const float* __restrict__ i_pre,
                            float* __restrict__ lfcs, float* __restrict__ mstab)
{
    const int bh = threadIdx.x;
    if (bh >= BB * NHH) return;
    const float* ip = i_pre + (size_t)bh * SS;
    float* lf = lfcs + (size_t)bh * SS;
    float* mm = mstab + (size_t)bh * SS;
    float c = 0.f, gmax = -1e30f;
    for (int s = 0; s < SS; s++) {
        c += lf[s];        // lf[s] holds log_fg on entry
        lf[s] = c;         // now cumulative
        const float g = ip[s] - c;
        gmax = fmaxf(gmax, g);
        mm[s] = c + gmax;  // m[t] = lf_cs[t] + max_{s<=t}(i_pre[s]-lf_cs[s])
    }
}

__device__ inline void fma4(float4& a, float s, const float4& b) {
    a.x += s * b.x; a.y += s * b.y; a.z += s * b.z; a.w += s * b.w;
}

// ---------------- Kernel 3: main mLSTM (flash-style, f32) ----------------
__global__ __launch_bounds__(256) void mlstm_kernel(
    const float* __restrict__ q, const float* __restrict__ k, const float* __restrict__ v,
    const float* __restrict__ i_pre, const float* __restrict__ lfcs,
    const float* __restrict__ mstab, const float* __restrict__ onw,
    float* __restrict__ out)
{
    __shared__ float q_s[TM][LDP];
    __shared__ float k_s[TS][LDP];
    __shared__ float v_s[TS][LDP];
    __shared__ float w_s[TM][WP];
    __shared__ float den_s[TM];
    __shared__ float ip_s[TS], lf_s[TS];

    const int tid = threadIdx.x;
    const int bh = blockIdx.y;
    const int b = bh / NHH, h = bh % NHH;
    const int t0 = blockIdx.x * TM;

    const float* qb = q + (size_t)b * SS * DIMM + h * DHH;
    const float* kb = k + (size_t)b * SS * DIMM + h * DHH;
    const float* vb = v + (size_t)b * SS * DIMM + h * DHH;

    // stage q tile (float4, coalesced)
    for (int idx = tid; idx < TM * DHH / 4; idx += 256) {
        const int r = idx >> 5, d4 = (idx & 31) * 4;
        *(float4*)&q_s[r][d4] = *(const float4*)&qb[(size_t)(t0 + r) * DIMM + d4];
    }
    if (tid < TM) den_s[tid] = 0.f;

    // score-phase mapping
    const int sr = tid >> 3;       // row 0..31
    const int cq = tid & 7;        // col group
    const float lft = lfcs[(size_t)bh * SS + t0 + sr];
    const float mt  = mstab[(size_t)bh * SS + t0 + sr];

    // PV-phase mapping
    const int dgrp = tid & 31;
    const int rgrp = tid >> 5;     // 0..7 -> rows rgrp*4..rgrp*4+3
    const int d0 = dgrp * 4;

    float4 numer[4];
    #pragma unroll
    for (int i = 0; i < 4; i++) numer[i] = make_float4(0.f, 0.f, 0.f, 0.f);

    const float inv_sqrt_dh = 0.08838834764831845f; // 1/sqrt(128)

    const int nst = blockIdx.x + 1;
    for (int st = 0; st < nst; st++) {
        const int s0 = st * TS;
        __syncthreads();
        // stage k, v tiles
        for (int idx = tid; idx < TS * DHH / 4; idx += 256) {
            const int r = idx >> 5, d4 = (idx & 31) * 4;
            *(float4*)&k_s[r][d4] = *(const float4*)&kb[(size_t)(s0 + r) * DIMM + d4];
            *(float4*)&v_s[r][d4] = *(const float4*)&vb[(size_t)(s0 + r) * DIMM + d4];
        }
        if (tid < TS) {
            ip_s[tid] = i_pre[(size_t)bh * SS + s0 + tid];
            lf_s[tid] = lfcs[(size_t)bh * SS + s0 + tid];
        }
        __syncthreads();

        // scores: thread -> row sr, cols cq+8*jj
        float sc[4] = {0.f, 0.f, 0.f, 0.f};
        for (int kk = 0; kk < DHH; kk += 4) {
            const float4 q4 = *(const float4*)&q_s[sr][kk];
            #pragma unroll
            for (int jj = 0; jj < 4; jj++) {
                const float4 k4 = *(const float4*)&k_s[cq + 8 * jj][kk];
                sc[jj] += q4.x * k4.x + q4.y * k4.y + q4.z * k4.z + q4.w * k4.w;
            }
        }
        float wpart = 0.f;
        #pragma unroll
        for (int jj = 0; jj < 4; jj++) {
            const int c = cq + 8 * jj;
            const int s_idx = s0 + c, t_idx = t0 + sr;
            float wv = 0.f;
            if (s_idx <= t_idx) {
                const float dec = lft - lf_s[c] + ip_s[c] - mt;  // <= 0 by construction
                wv = __expf(dec) * sc[jj] * inv_sqrt_dh;
            }
            w_s[sr][c] = wv;
            wpart += wv;
        }
        wpart += __shfl_xor(wpart, 1);
        wpart += __shfl_xor(wpart, 2);
        wpart += __shfl_xor(wpart, 4);
        if (cq == 0) den_s[sr] += wpart;
        __syncthreads();

        // PV: thread -> rows rgrp*4+i, dims d0..d0+3
        #pragma unroll
        for (int c4 = 0; c4 < TS / 4; c4++) {
            const float4 vv0 = *(const float4*)&v_s[c4 * 4 + 0][d0];
            const float4 vv1 = *(const float4*)&v_s[c4 * 4 + 1][d0];
            const float4 vv2 = *(const float4*)&v_s[c4 * 4 + 2][d0];
            const float4 vv3 = *(const float4*)&v_s[c4 * 4 + 3][d0];
            #pragma unroll
            for (int i = 0; i < 4; i++) {
                const float4 wv = *(const float4*)&w_s[rgrp * 4 + i][c4 * 4];
                fma4(numer[i], wv.x, vv0);
                fma4(numer[i], wv.y, vv1);
                fma4(numer[i], wv.z, vv2);
                fma4(numer[i], wv.w, vv3);
            }
        }
    }
    __syncthreads();

    // epilogue: denom + fused per-head RMSNorm (row fully within 32 lanes)
    float4 gain = *(const float4*)&onw[h * DHH + d0];
    gain.x += 1.f; gain.y += 1.f; gain.z += 1.f; gain.w += 1.f;
    float* ob = out + (size_t)b * SS * DIMM + h * DHH;

    #pragma unroll
    for (int i = 0; i < 4; i++) {
        const int r = rgrp * 4 + i;
        const int t = t0 + r;
        const float mtr = mstab[(size_t)bh * SS + t];
        const float denf = fmaxf(fabsf(den_s[r]), __expf(-mtr)) + B_EPS;
        const float inv = 1.0f / denf;
        float4 hv;
        hv.x = numer[i].x * inv; hv.y = numer[i].y * inv;
        hv.z = numer[i].z * inv; hv.w = numer[i].w * inv;
        float sq = hv.x * hv.x + hv.y * hv.y + hv.z * hv.z + hv.w * hv.w;
        sq += __shfl_xor(sq, 1); sq += __shfl_xor(sq, 2); sq += __shfl_xor(sq, 4);
        sq += __shfl_xor(sq, 8); sq += __shfl_xor(sq, 16);   // 32-lane row group
        const float rr = rsqrtf(sq * (1.0f / DHH) + N_EPS);
        float4 o4;
        o4.x = hv.x * rr * gain.x; o4.y = hv.y * rr * gain.y;
        o4.z = hv.z * rr * gain.z; o4.w = hv.w * rr * gain.w;
        *(float4*)&ob[(size_t)t * DIMM + d0] = o4;
    }
}

extern "C" void kernel_launch(void* const* d_in, const int* in_sizes, int n_in,
                              void* d_out, int out_size, void* d_ws, size_t ws_size,
                              hipStream_t stream) {
    const float* q   = (const float*)d_in[0];
    const float* k   = (const float*)d_in[1];
    const float* v   = (const float*)d_in[2];
    const float* gw  = (const float*)d_in[3];
    const float* gb  = (const float*)d_in[4];
    const float* onw = (const float*)d_in[5];
    float* out = (float*)d_out;

    float* ws    = (float*)d_ws;
    float* i_pre = ws;                          // B*NH*S
    float* lfcs  = ws + (size_t)BB * NHH * SS;  // B*NH*S (log_fg -> cumsum)
    float* mm    = ws + (size_t)2 * BB * NHH * SS;

    hipLaunchKernelGGL(gate_kernel, dim3(BB * SS / 4), dim3(256), 0, stream,
                       q, k, v, gw, gb, i_pre, lfcs);
    hipLaunchKernelGGL(scan_kernel, dim3(1), dim3(64), 0, stream, i_pre, lfcs, mm);
    hipLaunchKernelGGL(mlstm_kernel, dim3(SS / TM, BB * NHH), dim3(256), 0, stream,
                       q, k, v, i_pre, lfcs, mm, onw, out);
}

// Round 3
// 513.900 us; speedup vs baseline: 4.0525x; 4.0525x over previous
//
#include <hip/hip_runtime.h>
#include <math.h>

#define BB 2
#define SS 2048
#define DIMM 1024
#define NHH 8
#define DHH 128

constexpr float GATE_CAP = 15.0f;
constexpr float B_EPS = 5e-5f;
constexpr float N_EPS = 1e-6f;
constexpr float K_IS = 0.08838834764831845f; // 1/sqrt(128)

typedef _Float16 f16x8 __attribute__((ext_vector_type(8)));   // MFMA operand type
typedef __fp16  h16x2 __attribute__((ext_vector_type(2)));    // cvt_pkrtz result type
typedef float f32x4 __attribute__((ext_vector_type(4)));

union U8 { f16x8 v; h16x2 h[4]; unsigned int u[4]; };

// ---------------- Kernel 1: gate preactivations ----------------
__global__ __launch_bounds__(256) void gate_kernel(
    const float* __restrict__ q, const float* __restrict__ k, const float* __restrict__ v,
    const float* __restrict__ gw, const float* __restrict__ gb,
    float* __restrict__ i_pre, float* __restrict__ lfcs)
{
    const int tid = threadIdx.x;
    const int bs0 = blockIdx.x * 4;

    float acc[4][16];
    #pragma unroll
    for (int rr = 0; rr < 4; rr++)
        #pragma unroll
        for (int o = 0; o < 16; o++) acc[rr][o] = 0.f;

    for (int j = tid; j < 3 * DIMM; j += 256) {
        float x[4];
        #pragma unroll
        for (int rr = 0; rr < 4; rr++) {
            const int bs = bs0 + rr;
            float xv;
            if (j < DIMM)            xv = q[(size_t)bs * DIMM + j];
            else if (j < 2 * DIMM)   xv = k[(size_t)bs * DIMM + (j - DIMM)];
            else                     xv = v[(size_t)bs * DIMM + (j - 2 * DIMM)];
            x[rr] = xv;
        }
        #pragma unroll
        for (int o = 0; o < 16; o++) {
            const float wv = gw[o * 3 * DIMM + j];
            #pragma unroll
            for (int rr = 0; rr < 4; rr++) acc[rr][o] += wv * x[rr];
        }
    }

    __shared__ float red[4][4][16];
    const int lane = tid & 63, wave = tid >> 6;
    #pragma unroll
    for (int rr = 0; rr < 4; rr++) {
        #pragma unroll
        for (int o = 0; o < 16; o++) {
            float s = acc[rr][o];
            s += __shfl_xor(s, 32); s += __shfl_xor(s, 16); s += __shfl_xor(s, 8);
            s += __shfl_xor(s, 4);  s += __shfl_xor(s, 2);  s += __shfl_xor(s, 1);
            if (lane == 0) red[wave][rr][o] = s;
        }
    }
    __syncthreads();
    if (tid < 64) {
        const int rr = tid >> 4, o = tid & 15;
        float p = red[0][rr][o] + red[1][rr][o] + red[2][rr][o] + red[3][rr][o] + gb[o];
        p = GATE_CAP * tanhf(p / GATE_CAP);
        const int bs = bs0 + rr;
        const int b = bs / SS, s = bs % SS;
        if (o < NHH) {
            i_pre[((size_t)b * NHH + o) * SS + s] = p;
        } else {
            const int h = o - NHH;
            const float ls = (p >= 0.f) ? -log1pf(expf(-p)) : p - log1pf(expf(p));
            lfcs[((size_t)b * NHH + h) * SS + s] = ls;
        }
    }
}

// ---------------- Kernel 2: wave-parallel cumsum + prefix-max ----------------
__global__ void scan_kernel(const float* __restrict__ i_pre,
                            float* __restrict__ lfcs, float* __restrict__ mstab)
{
    const int bh = blockIdx.x;
    const int lane = threadIdx.x;
    const float* ip = i_pre + (size_t)bh * SS;
    float* lf = lfcs + (size_t)bh * SS;
    float* mm = mstab + (size_t)bh * SS;
    float csum = 0.f, gmax = -1e30f;
    for (int c0 = 0; c0 < SS; c0 += 64) {
        float vv = lf[c0 + lane];
        #pragma unroll
        for (int off = 1; off < 64; off <<= 1) {
            float n = __shfl_up(vv, off);
            if (lane >= off) vv += n;
        }
        const float c = vv + csum;
        lf[c0 + lane] = c;
        float gm = ip[c0 + lane] - c;
        #pragma unroll
        for (int off = 1; off < 64; off <<= 1) {
            float n = __shfl_up(gm, off);
            if (lane >= off) gm = fmaxf(gm, n);
        }
        gm = fmaxf(gm, gmax);
        mm[c0 + lane] = c + gm;
        csum = __shfl(c, 63);
        gmax = __shfl(gm, 63);
    }
}

// ---------------- Kernel 3: MFMA mLSTM ----------------
// S^T formulation: stacc = mfma(K_frag, Q_frag) -> lane holds S^T[s][t], t = lane&15 fixed.
// P repack to PV B-operand is lane-local via k-slot permutation sigma applied to both P and V.
__global__ __launch_bounds__(128, 2) void mlstm_kernel(
    const float* __restrict__ q, const float* __restrict__ k, const float* __restrict__ v,
    const float* __restrict__ i_pre, const float* __restrict__ lfcs,
    const float* __restrict__ mstab, const float* __restrict__ onw,
    float* __restrict__ out)
{
    __shared__ __align__(16) unsigned short k_s[64 * 128];  // [s][d] f16, byte ^ ((s&7)<<4)
    __shared__ __align__(16) unsigned short v8_s[64 * 128]; // [s/8][d][8] f16, byte ^ (((d>>3)&1)<<3)
    __shared__ float a_s[64];

    const int tid = threadIdx.x;
    const int lane = tid & 63;
    const int wv = tid >> 6;
    const int g = lane >> 4;
    const int l16 = lane & 15;

    // block decode: XCD-locality for bh + balanced heavy/light qt pairing
    const int id = blockIdx.x;
    const int x7 = id & 7;
    const int m5 = (id >> 3) & 31;
    const int hi = (id >> 8) & 1;
    const int bh = 2 * x7 + hi;
    const int qt = hi ? (31 - m5) : m5;
    const int b = bh >> 3, h = bh & 7;
    const int t0 = qt * 64;
    const int tw0 = t0 + 32 * wv;

    const size_t bhS = (size_t)bh * SS;
    const float* qp = q + (size_t)b * SS * DIMM + h * DHH;
    const float* kp = k + (size_t)b * SS * DIMM + h * DHH;
    const float* vp = v + (size_t)b * SS * DIMM + h * DHH;

    // Q fragments (B-operand) in registers + per-row scalars
    f16x8 qf[2][4];
    float cdec[2], mt_[2];
    #pragma unroll
    for (int nt = 0; nt < 2; ++nt) {
        const int t = tw0 + 16 * nt + l16;
        const float lft = lfcs[bhS + t];
        mt_[nt] = mstab[bhS + t];
        cdec[nt] = lft - mt_[nt];
        const float* qrow = qp + (size_t)t * DIMM;
        #pragma unroll
        for (int kb = 0; kb < 4; ++kb) {
            float4 x0 = *(const float4*)&qrow[kb * 32 + g * 8];
            float4 x1 = *(const float4*)&qrow[kb * 32 + g * 8 + 4];
            U8 u;
            u.h[0] = __builtin_amdgcn_cvt_pkrtz(x0.x, x0.y);
            u.h[1] = __builtin_amdgcn_cvt_pkrtz(x0.z, x0.w);
            u.h[2] = __builtin_amdgcn_cvt_pkrtz(x1.x, x1.y);
            u.h[3] = __builtin_amdgcn_cvt_pkrtz(x1.z, x1.w);
            qf[nt][kb] = u.v;
        }
    }

    f32x4 oacc[2][8];
    #pragma unroll
    for (int nt = 0; nt < 2; ++nt)
        #pragma unroll
        for (int mt = 0; mt < 8; ++mt)
            oacc[nt][mt] = (f32x4){0.f, 0.f, 0.f, 0.f};
    float dpart[2] = {0.f, 0.f};

    for (int st = 0; st <= qt; ++st) {
        const int s0 = st * 64;
        __syncthreads();
        // ---- stage K tile ----
        #pragma unroll
        for (int it = 0; it < 16; ++it) {
            const int item = it * 128 + tid;
            const int s = item >> 5, dq = item & 31;
            float4 kx = *(const float4*)&kp[(size_t)(s0 + s) * DIMM + dq * 4];
            h16x2 p0 = __builtin_amdgcn_cvt_pkrtz(kx.x, kx.y);
            h16x2 p1 = __builtin_amdgcn_cvt_pkrtz(kx.z, kx.w);
            uint2 wd;
            wd.x = __builtin_bit_cast(unsigned int, p0);
            wd.y = __builtin_bit_cast(unsigned int, p1);
            *(uint2*)((char*)k_s + ((s * 256 + dq * 8) ^ ((s & 7) << 4))) = wd;
        }
        // ---- stage V tile (s-blocked) ----
        #pragma unroll
        for (int it = 0; it < 8; ++it) {
            const int item = it * 128 + tid;
            const int sp = item >> 5, dq = item & 31;
            const int s = sp * 2, d0 = dq * 4;
            const float* r0 = &vp[(size_t)(s0 + s) * DIMM + d0];
            float4 a0 = *(const float4*)r0;
            float4 a1 = *(const float4*)(r0 + DIMM);
            const float e0[4] = {a0.x, a0.y, a0.z, a0.w};
            const float e1[4] = {a1.x, a1.y, a1.z, a1.w};
            #pragma unroll
            for (int di = 0; di < 4; ++di) {
                const int dd = d0 + di;
                h16x2 pr = __builtin_amdgcn_cvt_pkrtz(e0[di], e1[di]);
                const int byo = ((s >> 3) * 2048 + dd * 16 + (s & 7) * 2) ^ (((dd >> 3) & 1) << 3);
                *(unsigned int*)((char*)v8_s + byo) = __builtin_bit_cast(unsigned int, pr);
            }
        }
        if (tid < 64) a_s[tid] = i_pre[bhS + s0 + tid] - lfcs[bhS + s0 + tid];
        __syncthreads();

        // ---- QK^T (S^T tiles) ----
        f32x4 stacc[2][4];
        #pragma unroll
        for (int nt = 0; nt < 2; ++nt)
            #pragma unroll
            for (int ct = 0; ct < 4; ++ct)
                stacc[nt][ct] = (f32x4){0.f, 0.f, 0.f, 0.f};
        #pragma unroll
        for (int ct = 0; ct < 4; ++ct) {
            const int row = ct * 16 + l16;
            #pragma unroll
            for (int kb = 0; kb < 4; ++kb) {
                f16x8 kf = *(const f16x8*)((const char*)k_s +
                            ((row * 256 + kb * 64 + g * 16) ^ ((row & 7) << 4)));
                stacc[0][ct] = __builtin_amdgcn_mfma_f32_16x16x32_f16(kf, qf[0][kb], stacc[0][ct], 0, 0, 0);
                stacc[1][ct] = __builtin_amdgcn_mfma_f32_16x16x32_f16(kf, qf[1][kb], stacc[1][ct], 0, 0, 0);
            }
        }

        // ---- decay * score, causal mask, denominator partials ----
        f32x4 av[4];
        av[0] = *(const f32x4*)&a_s[g * 4];
        av[1] = *(const f32x4*)&a_s[16 + g * 4];
        av[2] = *(const f32x4*)&a_s[32 + g * 4];
        av[3] = *(const f32x4*)&a_s[48 + g * 4];
        const bool diag = (st == qt);
        #pragma unroll
        for (int nt = 0; nt < 2; ++nt) {
            float dsum = 0.f;
            #pragma unroll
            for (int ct = 0; ct < 4; ++ct) {
                #pragma unroll
                for (int i = 0; i < 4; ++i) {
                    const float e = K_IS * __expf(cdec[nt] + av[ct][i]);
                    float val = stacc[nt][ct][i] * e;
                    if (diag && (ct * 16 + g * 4 + i > wv * 32 + nt * 16 + l16)) val = 0.f;
                    dsum += val;
                    stacc[nt][ct][i] = val;
                }
            }
            dpart[nt] += dsum;
        }

        // ---- pack P to PV B-operand (lane-local, sigma-permuted k-slots) ----
        f16x8 pf[2][2];
        #pragma unroll
        for (int nt = 0; nt < 2; ++nt) {
            #pragma unroll
            for (int kb = 0; kb < 2; ++kb) {
                U8 u;
                u.h[0] = __builtin_amdgcn_cvt_pkrtz(stacc[nt][2 * kb][0],     stacc[nt][2 * kb][1]);
                u.h[1] = __builtin_amdgcn_cvt_pkrtz(stacc[nt][2 * kb][2],     stacc[nt][2 * kb][3]);
                u.h[2] = __builtin_amdgcn_cvt_pkrtz(stacc[nt][2 * kb + 1][0], stacc[nt][2 * kb + 1][1]);
                u.h[3] = __builtin_amdgcn_cvt_pkrtz(stacc[nt][2 * kb + 1][2], stacc[nt][2 * kb + 1][3]);
                pf[nt][kb] = u.v;
            }
        }

        // ---- PV: O^T accumulate (A = V fragments with matching sigma) ----
        #pragma unroll
        for (int mt = 0; mt < 8; ++mt) {
            const int d = mt * 16 + l16;
            #pragma unroll
            for (int kb = 0; kb < 2; ++kb) {
                const int base = (kb * 4 + (g >> 1)) * 2048 + d * 16 + (g & 1) * 8;
                const int f = ((d >> 3) & 1) << 3;
                uint2 lo = *(const uint2*)((const char*)v8_s + (base ^ f));
                uint2 hh = *(const uint2*)((const char*)v8_s + ((base + 2 * 2048) ^ f));
                U8 u;
                u.u[0] = lo.x; u.u[1] = lo.y; u.u[2] = hh.x; u.u[3] = hh.y;
                oacc[0][mt] = __builtin_amdgcn_mfma_f32_16x16x32_f16(u.v, pf[0][kb], oacc[0][mt], 0, 0, 0);
                oacc[1][mt] = __builtin_amdgcn_mfma_f32_16x16x32_f16(u.v, pf[1][kb], oacc[1][mt], 0, 0, 0);
            }
        }
    }

    // ---- epilogue: denom + fused per-head RMSNorm ----
    #pragma unroll
    for (int nt = 0; nt < 2; ++nt) {
        float den = dpart[nt];
        den += __shfl_xor(den, 16);
        den += __shfl_xor(den, 32);
        const float denf = fmaxf(fabsf(den), __expf(-mt_[nt])) + B_EPS;
        const float inv = 1.0f / denf;
        float ssq = 0.f;
        #pragma unroll
        for (int mt = 0; mt < 8; ++mt) {
            #pragma unroll
            for (int i = 0; i < 4; ++i) {
                const float hv2 = oacc[nt][mt][i] * inv;
                ssq += hv2 * hv2;
            }
        }
        ssq += __shfl_xor(ssq, 16);
        ssq += __shfl_xor(ssq, 32);
        const float rms = rsqrtf(ssq * (1.0f / DHH) + N_EPS);
        const int t = tw0 + 16 * nt + l16;
        float* orow = out + ((size_t)b * SS + t) * DIMM + h * DHH;
        #pragma unroll
        for (int mt = 0; mt < 8; ++mt) {
            float4 gn = *(const float4*)&onw[h * DHH + mt * 16 + g * 4];
            float4 o4;
            o4.x = oacc[nt][mt][0] * inv * rms * (1.f + gn.x);
            o4.y = oacc[nt][mt][1] * inv * rms * (1.f + gn.y);
            o4.z = oacc[nt][mt][2] * inv * rms * (1.f + gn.z);
            o4.w = oacc[nt][mt][3] * inv * rms * (1.f + gn.w);
            *(float4*)&orow[mt * 16 + g * 4] = o4;
        }
    }
}

extern "C" void kernel_launch(void* const* d_in, const int* in_sizes, int n_in,
                              void* d_out, int out_size, void* d_ws, size_t ws_size,
                              hipStream_t stream) {
    const float* q   = (const float*)d_in[0];
    const float* k   = (const float*)d_in[1];
    const float* v   = (const float*)d_in[2];
    const float* gw  = (const float*)d_in[3];
    const float* gb  = (const float*)d_in[4];
    const float* onw = (const float*)d_in[5];
    float* out = (float*)d_out;

    float* ws    = (float*)d_ws;
    float* i_pre = ws;
    float* lfcs  = ws + (size_t)BB * NHH * SS;
    float* mm    = ws + (size_t)2 * BB * NHH * SS;

    hipLaunchKernelGGL(gate_kernel, dim3(BB * SS / 4), dim3(256), 0, stream,
                       q, k, v, gw, gb, i_pre, lfcs);
    hipLaunchKernelGGL(scan_kernel, dim3(BB * NHH), dim3(64), 0, stream, i_pre, lfcs, mm);
    hipLaunchKernelGGL(mlstm_kernel, dim3(512), dim3(128), 0, stream,
                       q, k, v, i_pre, lfcs, mm, onw, out);
}

// Round 4
// 300.358 us; speedup vs baseline: 6.9336x; 1.7110x over previous
//
#include <hip/hip_runtime.h>
#include <math.h>

#define BB 2
#define SS 2048
#define DIMM 1024
#define NHH 8
#define DHH 128

constexpr float GATE_CAP = 15.0f;
constexpr float B_EPS = 5e-5f;
constexpr float N_EPS = 1e-6f;
constexpr float K_IS = 0.08838834764831845f; // 1/sqrt(128)

typedef _Float16 f16x8 __attribute__((ext_vector_type(8)));
typedef __fp16  h16x2 __attribute__((ext_vector_type(2)));
typedef float f32x4 __attribute__((ext_vector_type(4)));

union U8 { f16x8 v; h16x2 h[4]; unsigned int u[4]; };

__device__ inline unsigned short f2bf(float x) {
    unsigned u = __builtin_bit_cast(unsigned, x);
    unsigned r = (u + 0x7fff + ((u >> 16) & 1)) >> 16;   // RTNE
    return (unsigned short)r;
}
__device__ inline float bf2f(unsigned short s) {
    unsigned u = ((unsigned)s) << 16;
    return __builtin_bit_cast(float, u);
}

// ---------------- Kernel 1: gate preactivations (float4) ----------------
__global__ __launch_bounds__(256) void gate_kernel(
    const float* __restrict__ q, const float* __restrict__ k, const float* __restrict__ v,
    const float* __restrict__ gw, const float* __restrict__ gb,
    float* __restrict__ i_pre, float* __restrict__ lfcs)
{
    const int tid = threadIdx.x;
    const int bs0 = blockIdx.x * 4;

    float acc[4][16];
    #pragma unroll
    for (int rr = 0; rr < 4; rr++)
        #pragma unroll
        for (int o = 0; o < 16; o++) acc[rr][o] = 0.f;

    #pragma unroll
    for (int i = 0; i < 3; i++) {
        const float* src = (i == 0) ? q : ((i == 1) ? k : v);
        float4 x[4];
        #pragma unroll
        for (int rr = 0; rr < 4; rr++)
            x[rr] = *(const float4*)&src[(size_t)(bs0 + rr) * DIMM + tid * 4];
        #pragma unroll
        for (int o = 0; o < 16; o++) {
            const float4 w4 = *(const float4*)&gw[o * 3 * DIMM + i * DIMM + tid * 4];
            #pragma unroll
            for (int rr = 0; rr < 4; rr++)
                acc[rr][o] += x[rr].x * w4.x + x[rr].y * w4.y + x[rr].z * w4.z + x[rr].w * w4.w;
        }
    }

    __shared__ float red[4][4][16];
    const int lane = tid & 63, wave = tid >> 6;
    #pragma unroll
    for (int rr = 0; rr < 4; rr++) {
        #pragma unroll
        for (int o = 0; o < 16; o++) {
            float s = acc[rr][o];
            s += __shfl_xor(s, 32); s += __shfl_xor(s, 16); s += __shfl_xor(s, 8);
            s += __shfl_xor(s, 4);  s += __shfl_xor(s, 2);  s += __shfl_xor(s, 1);
            if (lane == 0) red[wave][rr][o] = s;
        }
    }
    __syncthreads();
    if (tid < 64) {
        const int rr = tid >> 4, o = tid & 15;
        float p = red[0][rr][o] + red[1][rr][o] + red[2][rr][o] + red[3][rr][o] + gb[o];
        p = GATE_CAP * tanhf(p / GATE_CAP);
        const int bs = bs0 + rr;
        const int b = bs / SS, s = bs % SS;
        if (o < NHH) {
            i_pre[((size_t)b * NHH + o) * SS + s] = p;
        } else {
            const int h = o - NHH;
            const float ls = (p >= 0.f) ? -log1pf(expf(-p)) : p - log1pf(expf(p));
            lfcs[((size_t)b * NHH + h) * SS + s] = ls;
        }
    }
}

// ---------------- Kernel 2: wave-parallel cumsum + prefix-max ----------------
__global__ void scan_kernel(const float* __restrict__ i_pre,
                            float* __restrict__ lfcs, float* __restrict__ mstab)
{
    const int bh = blockIdx.x;
    const int lane = threadIdx.x;
    const float* ip = i_pre + (size_t)bh * SS;
    float* lf = lfcs + (size_t)bh * SS;
    float* mm = mstab + (size_t)bh * SS;
    float csum = 0.f, gmax = -1e30f;
    for (int c0 = 0; c0 < SS; c0 += 64) {
        float vv = lf[c0 + lane];
        #pragma unroll
        for (int off = 1; off < 64; off <<= 1) {
            float n = __shfl_up(vv, off);
            if (lane >= off) vv += n;
        }
        const float c = vv + csum;
        lf[c0 + lane] = c;
        float gm = ip[c0 + lane] - c;
        #pragma unroll
        for (int off = 1; off < 64; off <<= 1) {
            float n = __shfl_up(gm, off);
            if (lane >= off) gm = fmaxf(gm, n);
        }
        gm = fmaxf(gm, gmax);
        mm[c0 + lane] = c + gm;
        csum = __shfl(c, 63);
        gmax = __shfl(gm, 63);
    }
}

// ---------------- Kernel 3: MFMA mLSTM, split-K over s ----------------
// Partial weights are UNSTABILIZED: w_raw = exp(lf[t]-lf[s]+i[s]) * score
// (bounded by e^m <= e^15 * score — safe in f32/bf16). reduce applies exp(-m[t]).
__global__ __launch_bounds__(128, 2) void mlstm_splitk(
    const float* __restrict__ q, const float* __restrict__ k, const float* __restrict__ v,
    const float* __restrict__ i_pre, const float* __restrict__ lfcs,
    unsigned short* __restrict__ pnum, float* __restrict__ pden)
{
    __shared__ __align__(16) unsigned short k_s[64 * 128];
    __shared__ __align__(16) unsigned short v8_s[64 * 128];
    __shared__ float a_s[64];

    const int tid = threadIdx.x;
    const int lane = tid & 63;
    const int wv = tid >> 6;
    const int g = lane >> 4;
    const int l16 = lane & 15;

    const int id = blockIdx.x;
    const int bh = id & 15;
    const int u = id >> 4;              // 0..143
    int G = 0;
    while (2 * (G + 1) * (G + 2) <= u) ++G;
    const int w0 = u - 2 * G * (G + 1);
    const int qd = w0 / (G + 1);
    const int qt = 4 * G + qd;
    const int chunk = w0 - qd * (G + 1);
    const int b = bh >> 3, h = bh & 7;
    const int tw0 = qt * 64 + 32 * wv;

    const size_t bhS = (size_t)bh * SS;
    const float* qp = q + (size_t)b * SS * DIMM + h * DHH;
    const float* kp = k + (size_t)b * SS * DIMM + h * DHH;
    const float* vp = v + (size_t)b * SS * DIMM + h * DHH;

    f16x8 qf[2][4];
    float cdec[2];
    #pragma unroll
    for (int nt = 0; nt < 2; ++nt) {
        const int t = tw0 + 16 * nt + l16;
        cdec[nt] = lfcs[bhS + t];              // raw lf[t]; -m applied in reduce
        const float* qrow = qp + (size_t)t * DIMM;
        #pragma unroll
        for (int kb = 0; kb < 4; ++kb) {
            float4 x0 = *(const float4*)&qrow[kb * 32 + g * 8];
            float4 x1 = *(const float4*)&qrow[kb * 32 + g * 8 + 4];
            U8 uu;
            uu.h[0] = __builtin_amdgcn_cvt_pkrtz(x0.x, x0.y);
            uu.h[1] = __builtin_amdgcn_cvt_pkrtz(x0.z, x0.w);
            uu.h[2] = __builtin_amdgcn_cvt_pkrtz(x1.x, x1.y);
            uu.h[3] = __builtin_amdgcn_cvt_pkrtz(x1.z, x1.w);
            qf[nt][kb] = uu.v;
        }
    }

    f32x4 oacc[2][8];
    #pragma unroll
    for (int nt = 0; nt < 2; ++nt)
        #pragma unroll
        for (int mt = 0; mt < 8; ++mt)
            oacc[nt][mt] = (f32x4){0.f, 0.f, 0.f, 0.f};
    float dpart[2] = {0.f, 0.f};

    const int st0 = chunk * 4;
    const int st1 = (st0 + 3 < qt) ? (st0 + 3) : qt;

    for (int st = st0; st <= st1; ++st) {
        const int s0 = st * 64;
        __syncthreads();
        #pragma unroll
        for (int it = 0; it < 16; ++it) {
            const int item = it * 128 + tid;
            const int s = item >> 5, dq = item & 31;
            float4 kx = *(const float4*)&kp[(size_t)(s0 + s) * DIMM + dq * 4];
            h16x2 p0 = __builtin_amdgcn_cvt_pkrtz(kx.x, kx.y);
            h16x2 p1 = __builtin_amdgcn_cvt_pkrtz(kx.z, kx.w);
            uint2 wd;
            wd.x = __builtin_bit_cast(unsigned int, p0);
            wd.y = __builtin_bit_cast(unsigned int, p1);
            *(uint2*)((char*)k_s + ((s * 256 + dq * 8) ^ ((s & 7) << 4))) = wd;
        }
        #pragma unroll
        for (int ws_ = 0; ws_ < 4; ++ws_) {
            const int sblk = ws_ * 2 + (tid >> 6);
            const int dd0 = (tid & 63) * 2;
            const int srow = s0 + sblk * 8;
            float2 e[8];
            #pragma unroll
            for (int j = 0; j < 8; ++j)
                e[j] = *(const float2*)&vp[(size_t)(srow + j) * DIMM + dd0];
            const int lo0 = (dd0 & 8) ? 4 : 0;
            const int hi0 = 4 - lo0;
            U8 u0, u1;
            u0.h[0] = __builtin_amdgcn_cvt_pkrtz(e[lo0 + 0].x, e[lo0 + 1].x);
            u0.h[1] = __builtin_amdgcn_cvt_pkrtz(e[lo0 + 2].x, e[lo0 + 3].x);
            u0.h[2] = __builtin_amdgcn_cvt_pkrtz(e[hi0 + 0].x, e[hi0 + 1].x);
            u0.h[3] = __builtin_amdgcn_cvt_pkrtz(e[hi0 + 2].x, e[hi0 + 3].x);
            u1.h[0] = __builtin_amdgcn_cvt_pkrtz(e[lo0 + 0].y, e[lo0 + 1].y);
            u1.h[1] = __builtin_amdgcn_cvt_pkrtz(e[lo0 + 2].y, e[lo0 + 3].y);
            u1.h[2] = __builtin_amdgcn_cvt_pkrtz(e[hi0 + 0].y, e[hi0 + 1].y);
            u1.h[3] = __builtin_amdgcn_cvt_pkrtz(e[hi0 + 2].y, e[hi0 + 3].y);
            *(f16x8*)((char*)v8_s + sblk * 2048 + dd0 * 16)      = u0.v;
            *(f16x8*)((char*)v8_s + sblk * 2048 + dd0 * 16 + 16) = u1.v;
        }
        if (tid < 64) a_s[tid] = i_pre[bhS + s0 + tid] - lfcs[bhS + s0 + tid];
        __syncthreads();

        f32x4 stacc[2][4];
        #pragma unroll
        for (int nt = 0; nt < 2; ++nt)
            #pragma unroll
            for (int ct = 0; ct < 4; ++ct)
                stacc[nt][ct] = (f32x4){0.f, 0.f, 0.f, 0.f};
        #pragma unroll
        for (int ct = 0; ct < 4; ++ct) {
            const int row = ct * 16 + l16;
            #pragma unroll
            for (int kb = 0; kb < 4; ++kb) {
                f16x8 kf = *(const f16x8*)((const char*)k_s +
                            ((row * 256 + kb * 64 + g * 16) ^ ((row & 7) << 4)));
                stacc[0][ct] = __builtin_amdgcn_mfma_f32_16x16x32_f16(kf, qf[0][kb], stacc[0][ct], 0, 0, 0);
                stacc[1][ct] = __builtin_amdgcn_mfma_f32_16x16x32_f16(kf, qf[1][kb], stacc[1][ct], 0, 0, 0);
            }
        }

        f32x4 av[4];
        av[0] = *(const f32x4*)&a_s[g * 4];
        av[1] = *(const f32x4*)&a_s[16 + g * 4];
        av[2] = *(const f32x4*)&a_s[32 + g * 4];
        av[3] = *(const f32x4*)&a_s[48 + g * 4];
        const bool diag = (st == qt);
        #pragma unroll
        for (int nt = 0; nt < 2; ++nt) {
            float dsum = 0.f;
            #pragma unroll
            for (int ct = 0; ct < 4; ++ct) {
                #pragma unroll
                for (int i = 0; i < 4; ++i) {
                    const float e = K_IS * __expf(cdec[nt] + av[ct][i]);
                    float val = stacc[nt][ct][i] * e;
                    if (diag && (ct * 16 + g * 4 + i > wv * 32 + nt * 16 + l16)) val = 0.f;
                    dsum += val;
                    stacc[nt][ct][i] = val;
                }
            }
            dpart[nt] += dsum;
        }

        f16x8 pf[2][2];
        #pragma unroll
        for (int nt = 0; nt < 2; ++nt) {
            #pragma unroll
            for (int kb = 0; kb < 2; ++kb) {
                U8 uu;
                uu.h[0] = __builtin_amdgcn_cvt_pkrtz(stacc[nt][2 * kb][0],     stacc[nt][2 * kb][1]);
                uu.h[1] = __builtin_amdgcn_cvt_pkrtz(stacc[nt][2 * kb][2],     stacc[nt][2 * kb][3]);
                uu.h[2] = __builtin_amdgcn_cvt_pkrtz(stacc[nt][2 * kb + 1][0], stacc[nt][2 * kb + 1][1]);
                uu.h[3] = __builtin_amdgcn_cvt_pkrtz(stacc[nt][2 * kb + 1][2], stacc[nt][2 * kb + 1][3]);
                pf[nt][kb] = uu.v;
            }
        }

        #pragma unroll
        for (int mt = 0; mt < 8; ++mt) {
            const int d = mt * 16 + l16;
            #pragma unroll
            for (int kb = 0; kb < 2; ++kb) {
                const int base = (kb * 4 + (g >> 1)) * 2048 + d * 16 + (g & 1) * 8;
                const int f = ((d >> 3) & 1) << 3;
                uint2 lo = *(const uint2*)((const char*)v8_s + (base ^ f));
                uint2 hh = *(const uint2*)((const char*)v8_s + ((base + 2 * 2048) ^ f));
                U8 uu;
                uu.u[0] = lo.x; uu.u[1] = lo.y; uu.u[2] = hh.x; uu.u[3] = hh.y;
                oacc[0][mt] = __builtin_amdgcn_mfma_f32_16x16x32_f16(uu.v, pf[0][kb], oacc[0][mt], 0, 0, 0);
                oacc[1][mt] = __builtin_amdgcn_mfma_f32_16x16x32_f16(uu.v, pf[1][kb], oacc[1][mt], 0, 0, 0);
            }
        }
    }

    const size_t cidx = (size_t)bh * 144 + u;
    #pragma unroll
    for (int nt = 0; nt < 2; ++nt) {
        float den = dpart[nt];
        den += __shfl_xor(den, 16);
        den += __shfl_xor(den, 32);
        const int row = wv * 32 + nt * 16 + l16;
        if (g == 0) pden[cidx * 64 + row] = den;
        #pragma unroll
        for (int mt = 0; mt < 8; ++mt) {
            ushort4 pk;
            pk.x = f2bf(oacc[nt][mt][0]);
            pk.y = f2bf(oacc[nt][mt][1]);
            pk.z = f2bf(oacc[nt][mt][2]);
            pk.w = f2bf(oacc[nt][mt][3]);
            *(ushort4*)&pnum[cidx * 8192 + (size_t)row * 128 + mt * 16 + g * 4] = pk;
        }
    }
}

// ---------------- Kernel 4: chunk reduction + denom + RMSNorm ----------------
__global__ __launch_bounds__(256) void reduce_kernel(
    const unsigned short* __restrict__ pnum, const float* __restrict__ pden,
    const float* __restrict__ mstab, const float* __restrict__ onw,
    float* __restrict__ out)
{
    const int id = blockIdx.x;          // 0..511
    const int bh = id & 15;
    const int qt = id >> 4;             // 0..31
    const int b = bh >> 3, h = bh & 7;
    const int tid = threadIdx.x;
    const int row = tid >> 2;
    const int qtr = tid & 3;
    const int G = qt >> 2;
    const int nch = G + 1;
    const int u0 = (G + 1) * (2 * G + (qt & 3));
    const size_t cbase = (size_t)bh * 144 + u0;

    float acc[32];
    #pragma unroll
    for (int i = 0; i < 32; ++i) acc[i] = 0.f;
    float den = 0.f;

    for (int c = 0; c < nch; ++c) {
        const ushort4* p = (const ushort4*)(pnum + (cbase + c) * 8192 + (size_t)row * 128 + qtr * 32);
        #pragma unroll
        for (int i2 = 0; i2 < 8; ++i2) {
            ushort4 t4 = p[i2];
            acc[i2 * 4 + 0] += bf2f(t4.x);
            acc[i2 * 4 + 1] += bf2f(t4.y);
            acc[i2 * 4 + 2] += bf2f(t4.z);
            acc[i2 * 4 + 3] += bf2f(t4.w);
        }
        den += pden[(cbase + c) * 64 + row];
    }

    const int t = qt * 64 + row;
    const float m = mstab[(size_t)bh * SS + t];
    const float em = __expf(-m);        // stabilizer applied post-hoc
    den *= em;
    const float denf = fmaxf(fabsf(den), em) + B_EPS;
    const float inv = em / denf;
    float ssq = 0.f;
    #pragma unroll
    for (int i = 0; i < 32; ++i) { acc[i] *= inv; ssq += acc[i] * acc[i]; }
    ssq += __shfl_xor(ssq, 1);
    ssq += __shfl_xor(ssq, 2);
    const float rms = rsqrtf(ssq * (1.0f / DHH) + N_EPS);

    float* orow = out + ((size_t)b * SS + t) * DIMM + h * DHH + qtr * 32;
    const float* gn = onw + h * DHH + qtr * 32;
    #pragma unroll
    for (int i4 = 0; i4 < 8; ++i4) {
        float4 g4 = *(const float4*)&gn[i4 * 4];
        float4 o4;
        o4.x = acc[i4 * 4 + 0] * rms * (1.f + g4.x);
        o4.y = acc[i4 * 4 + 1] * rms * (1.f + g4.y);
        o4.z = acc[i4 * 4 + 2] * rms * (1.f + g4.z);
        o4.w = acc[i4 * 4 + 3] * rms * (1.f + g4.w);
        *(float4*)&orow[i4 * 4] = o4;
    }
}

extern "C" void kernel_launch(void* const* d_in, const int* in_sizes, int n_in,
                              void* d_out, int out_size, void* d_ws, size_t ws_size,
                              hipStream_t stream) {
    const float* q   = (const float*)d_in[0];
    const float* k   = (const float*)d_in[1];
    const float* v   = (const float*)d_in[2];
    const float* gw  = (const float*)d_in[3];
    const float* gb  = (const float*)d_in[4];
    const float* onw = (const float*)d_in[5];
    float* out = (float*)d_out;

    float* ws    = (float*)d_ws;
    float* i_pre = ws;                          // 32768 f32
    float* lfcs  = ws + 32768;                  // 32768 f32
    float* mm    = ws + 65536;                  // 32768 f32
    float* pden  = ws + 98304;                  // 147456 f32
    unsigned short* pnum = (unsigned short*)(ws + 245760); // 2304*8192 bf16

    hipLaunchKernelGGL(gate_kernel, dim3(BB * SS / 4), dim3(256), 0, stream,
                       q, k, v, gw, gb, i_pre, lfcs);
    hipLaunchKernelGGL(scan_kernel, dim3(BB * NHH), dim3(64), 0, stream, i_pre, lfcs, mm);
    hipLaunchKernelGGL(mlstm_splitk, dim3(16 * 144), dim3(128), 0, stream,
                       q, k, v, i_pre, lfcs, pnum, pden);
    hipLaunchKernelGGL(reduce_kernel, dim3(16 * 32), dim3(256), 0, stream,
                       pnum, pden, mm, onw, out);
}

// Round 5
// 150.951 us; speedup vs baseline: 13.7963x; 1.9898x over previous
//
#include <hip/hip_runtime.h>
#include <math.h>

#define BB 2
#define SS 2048
#define DIMM 1024
#define NHH 8
#define DHH 128
#define NCHUNK 80   // chunks per bh (8-tile chunks)

constexpr float GATE_CAP = 15.0f;
constexpr float B_EPS = 5e-5f;
constexpr float N_EPS = 1e-6f;
constexpr float K_IS = 0.08838834764831845f; // 1/sqrt(128)

typedef _Float16 f16x8 __attribute__((ext_vector_type(8)));
typedef __fp16  h16x2 __attribute__((ext_vector_type(2)));
typedef float f32x4 __attribute__((ext_vector_type(4)));

union U8 { f16x8 v; h16x2 h[4]; unsigned int u[4]; };

__device__ inline unsigned short f2bf(float x) {
    unsigned u = __builtin_bit_cast(unsigned, x);
    unsigned r = (u + 0x7fff + ((u >> 16) & 1)) >> 16;   // RTNE
    return (unsigned short)r;
}
__device__ inline float bf2f(unsigned short s) {
    unsigned u = ((unsigned)s) << 16;
    return __builtin_bit_cast(float, u);
}

#define GLD_LDS16(gsrc, ldst)                                                   \
    __builtin_amdgcn_global_load_lds(                                           \
        (const __attribute__((address_space(1))) unsigned int*)(gsrc),          \
        (__attribute__((address_space(3))) unsigned int*)(ldst), 16, 0, 0)

// ---------------- Kernel 1: gate preactivations + k16 emit ----------------
__global__ __launch_bounds__(256) void gate_kernel(
    const float* __restrict__ q, const float* __restrict__ k, const float* __restrict__ v,
    const float* __restrict__ gw, const float* __restrict__ gb,
    float* __restrict__ i_pre, float* __restrict__ lfcs,
    unsigned short* __restrict__ k16)
{
    const int tid = threadIdx.x;
    const int bs0 = blockIdx.x * 4;
    const int d = tid * 4;          // 0..1023
    const int hh = d >> 7;          // head
    const int dd = d & 127;         // dim within head

    float acc[4][16];
    #pragma unroll
    for (int rr = 0; rr < 4; rr++)
        #pragma unroll
        for (int o = 0; o < 16; o++) acc[rr][o] = 0.f;

    #pragma unroll
    for (int i = 0; i < 3; i++) {
        const float* src = (i == 0) ? q : ((i == 1) ? k : v);
        float4 x[4];
        #pragma unroll
        for (int rr = 0; rr < 4; rr++)
            x[rr] = *(const float4*)&src[(size_t)(bs0 + rr) * DIMM + d];
        if (i == 1) {
            // emit k16: row-major f16 per (bh), swizzle baked: byte ^= (s&7)<<4
            #pragma unroll
            for (int rr = 0; rr < 4; rr++) {
                const int bs = bs0 + rr;
                const int b = bs / SS, s = bs % SS;
                const size_t bh = (size_t)b * NHH + hh;
                h16x2 p0 = __builtin_amdgcn_cvt_pkrtz(x[rr].x, x[rr].y);
                h16x2 p1 = __builtin_amdgcn_cvt_pkrtz(x[rr].z, x[rr].w);
                uint2 wd;
                wd.x = __builtin_bit_cast(unsigned int, p0);
                wd.y = __builtin_bit_cast(unsigned int, p1);
                const size_t byo = (bh * 2048 + s) * 256 + ((dd * 2) ^ ((s & 7) << 4));
                *(uint2*)((char*)k16 + byo) = wd;
            }
        }
        #pragma unroll
        for (int o = 0; o < 16; o++) {
            const float4 w4 = *(const float4*)&gw[o * 3 * DIMM + i * DIMM + d];
            #pragma unroll
            for (int rr = 0; rr < 4; rr++)
                acc[rr][o] += x[rr].x * w4.x + x[rr].y * w4.y + x[rr].z * w4.z + x[rr].w * w4.w;
        }
    }

    __shared__ float red[4][4][16];
    const int lane = tid & 63, wave = tid >> 6;
    #pragma unroll
    for (int rr = 0; rr < 4; rr++) {
        #pragma unroll
        for (int o = 0; o < 16; o++) {
            float s = acc[rr][o];
            s += __shfl_xor(s, 32); s += __shfl_xor(s, 16); s += __shfl_xor(s, 8);
            s += __shfl_xor(s, 4);  s += __shfl_xor(s, 2);  s += __shfl_xor(s, 1);
            if (lane == 0) red[wave][rr][o] = s;
        }
    }
    __syncthreads();
    if (tid < 64) {
        const int rr = tid >> 4, o = tid & 15;
        float p = red[0][rr][o] + red[1][rr][o] + red[2][rr][o] + red[3][rr][o] + gb[o];
        p = GATE_CAP * tanhf(p / GATE_CAP);
        const int bs = bs0 + rr;
        const int b = bs / SS, s = bs % SS;
        if (o < NHH) {
            i_pre[((size_t)b * NHH + o) * SS + s] = p;
        } else {
            const int h = o - NHH;
            const float ls = (p >= 0.f) ? -log1pf(expf(-p)) : p - log1pf(expf(p));
            lfcs[((size_t)b * NHH + h) * SS + s] = ls;
        }
    }
}

// ---------------- Kernel 2: V pre-transpose to PV fragment layout ----------------
// v16 per (bh, st): [d][off(s)] f16, off(s)=((s>>5)&1)*64+((s>>2)&3)*16+((s>>4)&1)*8+(s&3)*2 bytes,
// whole off XORed with ((d&7)<<4). PV A-frag (d, kb, g) = 16B at d*128 + ((kb*64+g*16)^((d&7)<<4)).
__global__ __launch_bounds__(128) void vprep_kernel(
    const float* __restrict__ v, unsigned short* __restrict__ v16)
{
    const int id = blockIdx.x;       // 16 bh * 32 st
    const int bh = id & 15;
    const int st = id >> 4;
    const int b = bh >> 3, h = bh & 7;
    const int tid = threadIdx.x;
    const int d2 = (tid & 63) * 2;
    const int kb = tid >> 6;         // s-half 0/1

    const float* vp = v + ((size_t)b * SS + st * 64 + kb * 32) * DIMM + h * DHH + d2;
    char* base = (char*)v16 + ((size_t)bh * 32 + st) * 16384;

    #pragma unroll
    for (int g = 0; g < 4; ++g) {
        float2 e[8];
        #pragma unroll
        for (int j = 0; j < 8; ++j) {
            const int s = 16 * (j >> 2) + 4 * g + (j & 3);
            e[j] = *(const float2*)&vp[(size_t)s * DIMM];
        }
        U8 u0, u1;
        u0.h[0] = __builtin_amdgcn_cvt_pkrtz(e[0].x, e[1].x);
        u0.h[1] = __builtin_amdgcn_cvt_pkrtz(e[2].x, e[3].x);
        u0.h[2] = __builtin_amdgcn_cvt_pkrtz(e[4].x, e[5].x);
        u0.h[3] = __builtin_amdgcn_cvt_pkrtz(e[6].x, e[7].x);
        u1.h[0] = __builtin_amdgcn_cvt_pkrtz(e[0].y, e[1].y);
        u1.h[1] = __builtin_amdgcn_cvt_pkrtz(e[2].y, e[3].y);
        u1.h[2] = __builtin_amdgcn_cvt_pkrtz(e[4].y, e[5].y);
        u1.h[3] = __builtin_amdgcn_cvt_pkrtz(e[6].y, e[7].y);
        const int p0 = kb * 64 + g * 16;
        *(f16x8*)(base + d2 * 128       + (p0 ^ ((d2 & 7) << 4)))       = u0.v;
        *(f16x8*)(base + (d2 + 1) * 128 + (p0 ^ (((d2 + 1) & 7) << 4))) = u1.v;
    }
}

// ---------------- Kernel 3: wave-parallel cumsum + prefix-max + aa ----------------
__global__ void scan_kernel(const float* __restrict__ i_pre,
                            float* __restrict__ lfcs, float* __restrict__ mstab,
                            float* __restrict__ aa)
{
    const int bh = blockIdx.x;
    const int lane = threadIdx.x;
    const float* ip = i_pre + (size_t)bh * SS;
    float* lf = lfcs + (size_t)bh * SS;
    float* mm = mstab + (size_t)bh * SS;
    float* ap = aa + (size_t)bh * SS;
    float csum = 0.f, gmax = -1e30f;
    for (int c0 = 0; c0 < SS; c0 += 64) {
        float vv = lf[c0 + lane];
        #pragma unroll
        for (int off = 1; off < 64; off <<= 1) {
            float n = __shfl_up(vv, off);
            if (lane >= off) vv += n;
        }
        const float c = vv + csum;
        lf[c0 + lane] = c;
        float gm = ip[c0 + lane] - c;
        ap[c0 + lane] = gm;
        #pragma unroll
        for (int off = 1; off < 64; off <<= 1) {
            float n = __shfl_up(gm, off);
            if (lane >= off) gm = fmaxf(gm, n);
        }
        gm = fmaxf(gm, gmax);
        mm[c0 + lane] = c + gm;
        csum = __shfl(c, 63);
        gmax = __shfl(gm, 63);
    }
}

// ---------------- Kernel 4: MFMA mLSTM split-K, gload_lds + dbuf prefetch ----------------
__global__ __launch_bounds__(128, 2) void mlstm_splitk(
    const float* __restrict__ q,
    const unsigned short* __restrict__ k16, const unsigned short* __restrict__ v16,
    const float* __restrict__ lfcs, const float* __restrict__ aa,
    unsigned short* __restrict__ pnum, float* __restrict__ pden)
{
    __shared__ __align__(16) unsigned short kbuf[2][8192];
    __shared__ __align__(16) unsigned short vbuf[2][8192];

    const int tid = threadIdx.x;
    const int lane = tid & 63;
    const int wv = tid >> 6;
    const int g = lane >> 4;
    const int l16 = lane & 15;

    const int id = blockIdx.x;
    const int bh = id & 15;                 // 2 bh per XCD
    const int u = NCHUNK - 1 - (id >> 4);   // heavy chunks launch first
    int G = 0;
    while (4 * (G + 1) * (G + 2) <= u) ++G;
    const int w0 = u - 4 * G * (G + 1);
    const int qd = w0 / (G + 1);
    const int qt = 8 * G + qd;
    const int chunk = w0 - qd * (G + 1);
    const int b = bh >> 3, h = bh & 7;
    const int tw0 = qt * 64 + 32 * wv;

    const size_t bhS = (size_t)bh * SS;
    const float* qp = q + (size_t)b * SS * DIMM + h * DHH;
    const char* kg = (const char*)k16 + (size_t)bh * 524288;
    const char* vg = (const char*)v16 + (size_t)bh * 524288;

    // Q fragments (f32 read, once per block) + raw decay scalar
    f16x8 qf[2][4];
    float cdec[2];
    #pragma unroll
    for (int nt = 0; nt < 2; ++nt) {
        const int t = tw0 + 16 * nt + l16;
        cdec[nt] = lfcs[bhS + t];           // raw lf[t]; exp(-m) applied in reduce
        const float* qrow = qp + (size_t)t * DIMM;
        #pragma unroll
        for (int kb = 0; kb < 4; ++kb) {
            float4 x0 = *(const float4*)&qrow[kb * 32 + g * 8];
            float4 x1 = *(const float4*)&qrow[kb * 32 + g * 8 + 4];
            U8 uu;
            uu.h[0] = __builtin_amdgcn_cvt_pkrtz(x0.x, x0.y);
            uu.h[1] = __builtin_amdgcn_cvt_pkrtz(x0.z, x0.w);
            uu.h[2] = __builtin_amdgcn_cvt_pkrtz(x1.x, x1.y);
            uu.h[3] = __builtin_amdgcn_cvt_pkrtz(x1.z, x1.w);
            qf[nt][kb] = uu.v;
        }
    }

    f32x4 oacc[2][8];
    #pragma unroll
    for (int nt = 0; nt < 2; ++nt)
        #pragma unroll
        for (int mt = 0; mt < 8; ++mt)
            oacc[nt][mt] = (f32x4){0.f, 0.f, 0.f, 0.f};
    float dpart[2] = {0.f, 0.f};

    const int st0 = chunk * 8;
    const int st1 = (st0 + 7 < qt) ? (st0 + 7) : qt;

    // stage: 16 linear global_load_lds (8 K + 8 V) per wave
    auto stage = [&](int bi, int st) {
        const char* ksrc = kg + (size_t)st * 16384;
        const char* vsrc = vg + (size_t)st * 16384;
        #pragma unroll
        for (int j = 0; j < 8; ++j) {
            const int off = (j * 2 + wv) * 1024;
            GLD_LDS16(ksrc + off + lane * 16, (char*)&kbuf[bi][0] + off);
            GLD_LDS16(vsrc + off + lane * 16, (char*)&vbuf[bi][0] + off);
        }
    };

    stage(0, st0);

    for (int st = st0; st <= st1; ++st) {
        const int cur = (st - st0) & 1;
        if (st < st1) {
            stage(cur ^ 1, st + 1);
            asm volatile("s_waitcnt vmcnt(16)" ::: "memory");
        } else {
            asm volatile("s_waitcnt vmcnt(0)" ::: "memory");
        }
        __builtin_amdgcn_s_barrier();
        __builtin_amdgcn_sched_barrier(0);

        const int s0 = st * 64;
        const float* ap = aa + bhS + s0;
        f32x4 av[4];
        av[0] = *(const f32x4*)&ap[g * 4];
        av[1] = *(const f32x4*)&ap[16 + g * 4];
        av[2] = *(const f32x4*)&ap[32 + g * 4];
        av[3] = *(const f32x4*)&ap[48 + g * 4];

        // ---- QK^T (S^T tiles) ----
        f32x4 stacc[2][4];
        #pragma unroll
        for (int nt = 0; nt < 2; ++nt)
            #pragma unroll
            for (int ct = 0; ct < 4; ++ct)
                stacc[nt][ct] = (f32x4){0.f, 0.f, 0.f, 0.f};
        #pragma unroll
        for (int ct = 0; ct < 4; ++ct) {
            const int row = ct * 16 + l16;
            #pragma unroll
            for (int kb = 0; kb < 4; ++kb) {
                f16x8 kf = *(const f16x8*)((const char*)&kbuf[cur][0] +
                            ((row * 256 + kb * 64 + g * 16) ^ ((row & 7) << 4)));
                stacc[0][ct] = __builtin_amdgcn_mfma_f32_16x16x32_f16(kf, qf[0][kb], stacc[0][ct], 0, 0, 0);
                stacc[1][ct] = __builtin_amdgcn_mfma_f32_16x16x32_f16(kf, qf[1][kb], stacc[1][ct], 0, 0, 0);
            }
        }

        // ---- decay * score, causal mask, denominator partials ----
        const bool diag = (st == qt);
        #pragma unroll
        for (int nt = 0; nt < 2; ++nt) {
            float dsum = 0.f;
            #pragma unroll
            for (int ct = 0; ct < 4; ++ct) {
                #pragma unroll
                for (int i = 0; i < 4; ++i) {
                    const float e = K_IS * __expf(cdec[nt] + av[ct][i]);
                    float val = stacc[nt][ct][i] * e;
                    if (diag && (ct * 16 + g * 4 + i > wv * 32 + nt * 16 + l16)) val = 0.f;
                    dsum += val;
                    stacc[nt][ct][i] = val;
                }
            }
            dpart[nt] += dsum;
        }

        // ---- pack P (lane-local, sigma k-slots) ----
        f16x8 pf[2][2];
        #pragma unroll
        for (int nt = 0; nt < 2; ++nt) {
            #pragma unroll
            for (int kb = 0; kb < 2; ++kb) {
                U8 uu;
                uu.h[0] = __builtin_amdgcn_cvt_pkrtz(stacc[nt][2 * kb][0],     stacc[nt][2 * kb][1]);
                uu.h[1] = __builtin_amdgcn_cvt_pkrtz(stacc[nt][2 * kb][2],     stacc[nt][2 * kb][3]);
                uu.h[2] = __builtin_amdgcn_cvt_pkrtz(stacc[nt][2 * kb + 1][0], stacc[nt][2 * kb + 1][1]);
                uu.h[3] = __builtin_amdgcn_cvt_pkrtz(stacc[nt][2 * kb + 1][2], stacc[nt][2 * kb + 1][3]);
                pf[nt][kb] = uu.v;
            }
        }

        // ---- PV: single b128 V-frag reads (sigma-matched layout) ----
        #pragma unroll
        for (int mt = 0; mt < 8; ++mt) {
            const int dI = mt * 16 + l16;
            #pragma unroll
            for (int kb = 0; kb < 2; ++kb) {
                f16x8 vf = *(const f16x8*)((const char*)&vbuf[cur][0] +
                            dI * 128 + ((kb * 64 + g * 16) ^ ((dI & 7) << 4)));
                oacc[0][mt] = __builtin_amdgcn_mfma_f32_16x16x32_f16(vf, pf[0][kb], oacc[0][mt], 0, 0, 0);
                oacc[1][mt] = __builtin_amdgcn_mfma_f32_16x16x32_f16(vf, pf[1][kb], oacc[1][mt], 0, 0, 0);
            }
        }
        __builtin_amdgcn_sched_barrier(0);
        __builtin_amdgcn_s_barrier();
    }

    // ---- epilogue: coalesced fragment-order partials ----
    const size_t cidx = (size_t)bh * NCHUNK + u;
    #pragma unroll
    for (int nt = 0; nt < 2; ++nt) {
        float den = dpart[nt];
        den += __shfl_xor(den, 16);
        den += __shfl_xor(den, 32);
        const int row = wv * 32 + nt * 16 + l16;
        if (g == 0) pden[cidx * 64 + row] = den;
        #pragma unroll
        for (int mt = 0; mt < 8; ++mt) {
            ushort4 pk;
            pk.x = f2bf(oacc[nt][mt][0]);
            pk.y = f2bf(oacc[nt][mt][1]);
            pk.z = f2bf(oacc[nt][mt][2]);
            pk.w = f2bf(oacc[nt][mt][3]);
            *(ushort4*)&pnum[((cidx * 32 + wv * 16 + nt * 8 + mt) << 8) + lane * 4] = pk;
        }
    }
}

// ---------------- Kernel 5: chunk reduction + denom + RMSNorm ----------------
__global__ __launch_bounds__(128) void reduce_kernel(
    const unsigned short* __restrict__ pnum, const float* __restrict__ pden,
    const float* __restrict__ mstab, const float* __restrict__ onw,
    float* __restrict__ out)
{
    const int id = blockIdx.x;          // 16*32
    const int bh = id & 15;
    const int qt = id >> 4;
    const int b = bh >> 3, h = bh & 7;
    const int tid = threadIdx.x;
    const int lane = tid & 63;
    const int wv = tid >> 6;
    const int g = lane >> 4;
    const int l16 = lane & 15;

    const int G = qt >> 3;
    const int nch = G + 1;
    const int u0 = 4 * G * (G + 1) + (qt & 7) * (G + 1);
    const size_t cbase = (size_t)bh * NCHUNK + u0;

    f32x4 acc[2][8];
    #pragma unroll
    for (int nt = 0; nt < 2; ++nt)
        #pragma unroll
        for (int mt = 0; mt < 8; ++mt)
            acc[nt][mt] = (f32x4){0.f, 0.f, 0.f, 0.f};
    float den[2] = {0.f, 0.f};

    for (int c = 0; c < nch; ++c) {
        const size_t fb = (cbase + c) * 32 + wv * 16;
        #pragma unroll
        for (int nt = 0; nt < 2; ++nt) {
            #pragma unroll
            for (int mt = 0; mt < 8; ++mt) {
                ushort4 t4 = *(const ushort4*)&pnum[((fb + nt * 8 + mt) << 8) + lane * 4];
                acc[nt][mt][0] += bf2f(t4.x);
                acc[nt][mt][1] += bf2f(t4.y);
                acc[nt][mt][2] += bf2f(t4.z);
                acc[nt][mt][3] += bf2f(t4.w);
            }
            den[nt] += pden[(cbase + c) * 64 + wv * 32 + nt * 16 + l16];
        }
    }

    #pragma unroll
    for (int nt = 0; nt < 2; ++nt) {
        const int t = qt * 64 + wv * 32 + nt * 16 + l16;
        const float m = mstab[(size_t)bh * SS + t];
        const float em = __expf(-m);
        const float dt = den[nt] * em;
        const float denf = fmaxf(fabsf(dt), em) + B_EPS;
        const float inv = em / denf;
        float ssq = 0.f;
        #pragma unroll
        for (int mt = 0; mt < 8; ++mt) {
            #pragma unroll
            for (int i = 0; i < 4; ++i) {
                acc[nt][mt][i] *= inv;
                ssq += acc[nt][mt][i] * acc[nt][mt][i];
            }
        }
        ssq += __shfl_xor(ssq, 16);
        ssq += __shfl_xor(ssq, 32);
        const float rms = rsqrtf(ssq * (1.0f / DHH) + N_EPS);

        float* orow = out + ((size_t)b * SS + t) * DIMM + h * DHH;
        #pragma unroll
        for (int mt = 0; mt < 8; ++mt) {
            float4 gn = *(const float4*)&onw[h * DHH + mt * 16 + g * 4];
            float4 o4;
            o4.x = acc[nt][mt][0] * rms * (1.f + gn.x);
            o4.y = acc[nt][mt][1] * rms * (1.f + gn.y);
            o4.z = acc[nt][mt][2] * rms * (1.f + gn.z);
            o4.w = acc[nt][mt][3] * rms * (1.f + gn.w);
            *(float4*)&orow[mt * 16 + g * 4] = o4;
        }
    }
}

extern "C" void kernel_launch(void* const* d_in, const int* in_sizes, int n_in,
                              void* d_out, int out_size, void* d_ws, size_t ws_size,
                              hipStream_t stream) {
    const float* q   = (const float*)d_in[0];
    const float* k   = (const float*)d_in[1];
    const float* v   = (const float*)d_in[2];
    const float* gw  = (const float*)d_in[3];
    const float* gb  = (const float*)d_in[4];
    const float* onw = (const float*)d_in[5];
    float* out = (float*)d_out;

    float* ws    = (float*)d_ws;
    float* i_pre = ws;                  // 32768 f32
    float* lfcs  = ws + 32768;          // 32768
    float* mm    = ws + 65536;          // 32768
    float* aa    = ws + 98304;          // 32768
    float* pden  = ws + 131072;         // 81920 (ends at f32 212992 < 262144)
    unsigned short* pnum = (unsigned short*)((char*)d_ws + 1048576);   // 20971520 B
    unsigned short* k16  = (unsigned short*)((char*)d_ws + 22020096);  // 8388608 B
    unsigned short* v16  = (unsigned short*)((char*)d_ws + 30408704);  // 8388608 B -> end 38797312

    hipLaunchKernelGGL(gate_kernel, dim3(BB * SS / 4), dim3(256), 0, stream,
                       q, k, v, gw, gb, i_pre, lfcs, k16);
    hipLaunchKernelGGL(vprep_kernel, dim3(16 * 32), dim3(128), 0, stream, v, v16);
    hipLaunchKernelGGL(scan_kernel, dim3(BB * NHH), dim3(64), 0, stream, i_pre, lfcs, mm, aa);
    hipLaunchKernelGGL(mlstm_splitk, dim3(16 * NCHUNK), dim3(128), 0, stream,
                       q, k16, v16, lfcs, aa, pnum, pden);
    hipLaunchKernelGGL(reduce_kernel, dim3(16 * 32), dim3(128), 0, stream,
                       pnum, pden, mm, onw, out);
}

// Round 6
// 108.915 us; speedup vs baseline: 19.1210x; 1.3860x over previous
//
#include <hip/hip_runtime.h>
#include <math.h>

#define BB 2
#define SS 2048
#define DIMM 1024
#define NHH 8
#define DHH 128

constexpr float GATE_CAP = 15.0f;
constexpr float B_EPS = 5e-5f;
constexpr float N_EPS = 1e-6f;
constexpr float K_IS = 0.08838834764831845f; // 1/sqrt(128)

typedef _Float16 f16x8 __attribute__((ext_vector_type(8)));
typedef __fp16  h16x2 __attribute__((ext_vector_type(2)));
typedef float f32x4 __attribute__((ext_vector_type(4)));

union U8 { f16x8 v; h16x2 h[4]; unsigned int u[4]; };

__device__ inline unsigned short f2bf(float x) {
    unsigned u = __builtin_bit_cast(unsigned, x);
    unsigned r = (u + 0x7fff + ((u >> 16) & 1)) >> 16;   // RTNE
    return (unsigned short)r;
}
__device__ inline float bf2f(unsigned short s) {
    unsigned u = ((unsigned)s) << 16;
    return __builtin_bit_cast(float, u);
}

#define GLD_LDS16(gsrc, ldst)                                                   \
    __builtin_amdgcn_global_load_lds(                                           \
        (const __attribute__((address_space(1))) unsigned int*)(gsrc),          \
        (__attribute__((address_space(3))) unsigned int*)(ldst), 16, 0, 0)

// ---------------- Kernel 1: gate preactivations + k16 emit ----------------
__global__ __launch_bounds__(256) void gate_kernel(
    const float* __restrict__ q, const float* __restrict__ k, const float* __restrict__ v,
    const float* __restrict__ gw, const float* __restrict__ gb,
    float* __restrict__ i_pre, float* __restrict__ lfcs,
    unsigned short* __restrict__ k16)
{
    const int tid = threadIdx.x;
    const int bs0 = blockIdx.x * 4;
    const int d = tid * 4;          // 0..1023
    const int hh = d >> 7;          // head
    const int dd = d & 127;         // dim within head

    float acc[4][16];
    #pragma unroll
    for (int rr = 0; rr < 4; rr++)
        #pragma unroll
        for (int o = 0; o < 16; o++) acc[rr][o] = 0.f;

    #pragma unroll
    for (int i = 0; i < 3; i++) {
        const float* src = (i == 0) ? q : ((i == 1) ? k : v);
        float4 x[4];
        #pragma unroll
        for (int rr = 0; rr < 4; rr++)
            x[rr] = *(const float4*)&src[(size_t)(bs0 + rr) * DIMM + d];
        if (i == 1) {
            #pragma unroll
            for (int rr = 0; rr < 4; rr++) {
                const int bs = bs0 + rr;
                const int b = bs / SS, s = bs % SS;
                const size_t bh = (size_t)b * NHH + hh;
                h16x2 p0 = __builtin_amdgcn_cvt_pkrtz(x[rr].x, x[rr].y);
                h16x2 p1 = __builtin_amdgcn_cvt_pkrtz(x[rr].z, x[rr].w);
                uint2 wd;
                wd.x = __builtin_bit_cast(unsigned int, p0);
                wd.y = __builtin_bit_cast(unsigned int, p1);
                const size_t byo = (bh * 2048 + s) * 256 + ((dd * 2) ^ ((s & 7) << 4));
                *(uint2*)((char*)k16 + byo) = wd;
            }
        }
        #pragma unroll
        for (int o = 0; o < 16; o++) {
            const float4 w4 = *(const float4*)&gw[o * 3 * DIMM + i * DIMM + d];
            #pragma unroll
            for (int rr = 0; rr < 4; rr++)
                acc[rr][o] += x[rr].x * w4.x + x[rr].y * w4.y + x[rr].z * w4.z + x[rr].w * w4.w;
        }
    }

    __shared__ float red[4][4][16];
    const int lane = tid & 63, wave = tid >> 6;
    #pragma unroll
    for (int rr = 0; rr < 4; rr++) {
        #pragma unroll
        for (int o = 0; o < 16; o++) {
            float s = acc[rr][o];
            s += __shfl_xor(s, 32); s += __shfl_xor(s, 16); s += __shfl_xor(s, 8);
            s += __shfl_xor(s, 4);  s += __shfl_xor(s, 2);  s += __shfl_xor(s, 1);
            if (lane == 0) red[wave][rr][o] = s;
        }
    }
    __syncthreads();
    if (tid < 64) {
        const int rr = tid >> 4, o = tid & 15;
        float p = red[0][rr][o] + red[1][rr][o] + red[2][rr][o] + red[3][rr][o] + gb[o];
        p = GATE_CAP * tanhf(p / GATE_CAP);
        const int bs = bs0 + rr;
        const int b = bs / SS, s = bs % SS;
        if (o < NHH) {
            i_pre[((size_t)b * NHH + o) * SS + s] = p;
        } else {
            const int h = o - NHH;
            const float ls = (p >= 0.f) ? -log1pf(expf(-p)) : p - log1pf(expf(p));
            lfcs[((size_t)b * NHH + h) * SS + s] = ls;
        }
    }
}

// ---------------- Kernel 2: V pre-transpose to PV fragment layout ----------------
__global__ __launch_bounds__(128) void vprep_kernel(
    const float* __restrict__ v, unsigned short* __restrict__ v16)
{
    const int id = blockIdx.x;       // 16 bh * 32 st
    const int bh = id & 15;
    const int st = id >> 4;
    const int b = bh >> 3, h = bh & 7;
    const int tid = threadIdx.x;
    const int d2 = (tid & 63) * 2;
    const int kb = tid >> 6;         // s-half 0/1

    const float* vp = v + ((size_t)b * SS + st * 64 + kb * 32) * DIMM + h * DHH + d2;
    char* base = (char*)v16 + ((size_t)bh * 32 + st) * 16384;

    #pragma unroll
    for (int g = 0; g < 4; ++g) {
        float2 e[8];
        #pragma unroll
        for (int j = 0; j < 8; ++j) {
            const int s = 16 * (j >> 2) + 4 * g + (j & 3);
            e[j] = *(const float2*)&vp[(size_t)s * DIMM];
        }
        U8 u0, u1;
        u0.h[0] = __builtin_amdgcn_cvt_pkrtz(e[0].x, e[1].x);
        u0.h[1] = __builtin_amdgcn_cvt_pkrtz(e[2].x, e[3].x);
        u0.h[2] = __builtin_amdgcn_cvt_pkrtz(e[4].x, e[5].x);
        u0.h[3] = __builtin_amdgcn_cvt_pkrtz(e[6].x, e[7].x);
        u1.h[0] = __builtin_amdgcn_cvt_pkrtz(e[0].y, e[1].y);
        u1.h[1] = __builtin_amdgcn_cvt_pkrtz(e[2].y, e[3].y);
        u1.h[2] = __builtin_amdgcn_cvt_pkrtz(e[4].y, e[5].y);
        u1.h[3] = __builtin_amdgcn_cvt_pkrtz(e[6].y, e[7].y);
        const int p0 = kb * 64 + g * 16;
        *(f16x8*)(base + d2 * 128       + (p0 ^ ((d2 & 7) << 4)))       = u0.v;
        *(f16x8*)(base + (d2 + 1) * 128 + (p0 ^ (((d2 + 1) & 7) << 4))) = u1.v;
    }
}

// ---------------- Kernel 3: block-parallel cumsum + prefix-max ----------------
__global__ __launch_bounds__(256) void scan_kernel(
    const float* __restrict__ i_pre,
    float* __restrict__ lfcs, float* __restrict__ mstab, float* __restrict__ aa)
{
    const int bh = blockIdx.x;
    const int tid = threadIdx.x;
    const int lane = tid & 63, wv = tid >> 6;
    const size_t base = (size_t)bh * SS + tid * 8;

    float x[8];
    {
        float4 a0 = *(const float4*)&lfcs[base];
        float4 a1 = *(const float4*)&lfcs[base + 4];
        x[0] = a0.x; x[1] = a0.y; x[2] = a0.z; x[3] = a0.w;
        x[4] = a1.x; x[5] = a1.y; x[6] = a1.z; x[7] = a1.w;
    }
    #pragma unroll
    for (int i = 1; i < 8; ++i) x[i] += x[i - 1];   // local inclusive cumsum

    // wave-level exclusive scan of thread totals
    const float tot = x[7];
    float inc = tot;
    #pragma unroll
    for (int off = 1; off < 64; off <<= 1) {
        float n = __shfl_up(inc, off);
        if (lane >= off) inc += n;
    }
    const float exc = inc - tot;

    __shared__ float wt[4], wm[4];
    if (lane == 63) wt[wv] = inc;
    __syncthreads();
    float wpre = 0.f;
    for (int w = 0; w < 4; ++w) if (w < wv) wpre += wt[w];
    const float off0 = exc + wpre;
    #pragma unroll
    for (int i = 0; i < 8; ++i) x[i] += off0;       // final lf_cs
    {
        float4 s0 = {x[0], x[1], x[2], x[3]}, s1 = {x[4], x[5], x[6], x[7]};
        *(float4*)&lfcs[base] = s0;
        *(float4*)&lfcs[base + 4] = s1;
    }

    // g = i_pre - lf_cs; prefix max
    float g[8];
    {
        float4 i0 = *(const float4*)&i_pre[base];
        float4 i1 = *(const float4*)&i_pre[base + 4];
        g[0] = i0.x - x[0]; g[1] = i0.y - x[1]; g[2] = i0.z - x[2]; g[3] = i0.w - x[3];
        g[4] = i1.x - x[4]; g[5] = i1.y - x[5]; g[6] = i1.z - x[6]; g[7] = i1.w - x[7];
        float4 s0 = {g[0], g[1], g[2], g[3]}, s1 = {g[4], g[5], g[6], g[7]};
        *(float4*)&aa[base] = s0;
        *(float4*)&aa[base + 4] = s1;
    }
    float mg[8];
    mg[0] = g[0];
    #pragma unroll
    for (int i = 1; i < 8; ++i) mg[i] = fmaxf(mg[i - 1], g[i]);

    float minc = mg[7];
    #pragma unroll
    for (int off = 1; off < 64; off <<= 1) {
        float n = __shfl_up(minc, off);
        if (lane >= off) minc = fmaxf(minc, n);
    }
    float mexc = __shfl_up(minc, 1);
    if (lane == 0) mexc = -1e30f;
    if (lane == 63) wm[wv] = minc;
    __syncthreads();
    float wmpre = -1e30f;
    for (int w = 0; w < 4; ++w) if (w < wv) wmpre = fmaxf(wmpre, wm[w]);
    const float pm = fmaxf(mexc, wmpre);
    float4 s0, s1;
    s0.x = x[0] + fmaxf(pm, mg[0]); s0.y = x[1] + fmaxf(pm, mg[1]);
    s0.z = x[2] + fmaxf(pm, mg[2]); s0.w = x[3] + fmaxf(pm, mg[3]);
    s1.x = x[4] + fmaxf(pm, mg[4]); s1.y = x[5] + fmaxf(pm, mg[5]);
    s1.z = x[6] + fmaxf(pm, mg[6]); s1.w = x[7] + fmaxf(pm, mg[7]);
    *(float4*)&mstab[base] = s0;
    *(float4*)&mstab[base + 4] = s1;
}

// ---------------- Kernel 4: MFMA mLSTM split-K (256 thr, 128 t-rows) ----------------
// 480 blocks: ids 0..255 = heavy (12-tile) chunks, one per CU; 256..479 = light.
__global__ __launch_bounds__(256, 2) void mlstm_splitk(
    const float* __restrict__ q,
    const unsigned short* __restrict__ k16, const unsigned short* __restrict__ v16,
    const float* __restrict__ lfcs, const float* __restrict__ aa,
    unsigned short* __restrict__ pnum, float* __restrict__ pden)
{
    __shared__ __align__(16) unsigned short kbuf[2][8192];
    __shared__ __align__(16) unsigned short vbuf[2][8192];

    const int tid = threadIdx.x;
    const int lane = tid & 63;
    const int wv = tid >> 6;
    const int g = lane >> 4;
    const int l16 = lane & 15;

    // ---- decode (bh, qq, chunk): heavy-first balanced dispatch ----
    const int id = blockIdx.x;
    int bh, qq, chunk;
    if (id < 256) {
        bh = id & 15;
        const int j = id >> 4;                 // 0..15
        if (j < 7)       { qq = 5 + j;               chunk = 0; }
        else if (j == 7) { qq = 11;                  chunk = 1; }
        else             { qq = 12 + ((j - 8) >> 1); chunk = (j - 8) & 1; }
    } else {
        const int e = id - 256;
        bh = e & 15;
        const int j = e >> 4;                  // 0..13
        if (j < 5)       { qq = j;            chunk = 0; }
        else if (j < 10) { qq = 6 + (j - 5);  chunk = 1; }
        else             { qq = 12 + (j - 10); chunk = 2; }
    }
    const int b = bh >> 3, h = bh & 7;
    const int tw0 = qq * 128 + 32 * wv;

    const size_t bhS = (size_t)bh * SS;
    const float* qp = q + (size_t)b * SS * DIMM + h * DHH;
    const char* kg = (const char*)k16 + (size_t)bh * 524288;
    const char* vg = (const char*)v16 + (size_t)bh * 524288;

    // Q fragments + raw decay scalar
    f16x8 qf[2][4];
    float cdec[2];
    #pragma unroll
    for (int nt = 0; nt < 2; ++nt) {
        const int t = tw0 + 16 * nt + l16;
        cdec[nt] = lfcs[bhS + t];
        const float* qrow = qp + (size_t)t * DIMM;
        #pragma unroll
        for (int kb = 0; kb < 4; ++kb) {
            float4 x0 = *(const float4*)&qrow[kb * 32 + g * 8];
            float4 x1 = *(const float4*)&qrow[kb * 32 + g * 8 + 4];
            U8 uu;
            uu.h[0] = __builtin_amdgcn_cvt_pkrtz(x0.x, x0.y);
            uu.h[1] = __builtin_amdgcn_cvt_pkrtz(x0.z, x0.w);
            uu.h[2] = __builtin_amdgcn_cvt_pkrtz(x1.x, x1.y);
            uu.h[3] = __builtin_amdgcn_cvt_pkrtz(x1.z, x1.w);
            qf[nt][kb] = uu.v;
        }
    }

    f32x4 oacc[2][8];
    #pragma unroll
    for (int nt = 0; nt < 2; ++nt)
        #pragma unroll
        for (int mt = 0; mt < 8; ++mt)
            oacc[nt][mt] = (f32x4){0.f, 0.f, 0.f, 0.f};
    float dpart[2] = {0.f, 0.f};

    const int st0 = chunk * 12;
    const int st1m = 2 * qq + 1;
    const int st1 = (st0 + 11 < st1m) ? (st0 + 11) : st1m;

    // stage: 8 linear global_load_lds per wave (4 K + 4 V), 32KB total per tile
    auto stage = [&](int bi, int st) {
        const char* ksrc = kg + (size_t)st * 16384;
        const char* vsrc = vg + (size_t)st * 16384;
        #pragma unroll
        for (int j = 0; j < 4; ++j) {
            const int off = (j * 4 + wv) * 1024;
            GLD_LDS16(ksrc + off + lane * 16, (char*)&kbuf[bi][0] + off);
            GLD_LDS16(vsrc + off + lane * 16, (char*)&vbuf[bi][0] + off);
        }
    };

    stage(0, st0);

    for (int st = st0; st <= st1; ++st) {
        const int cur = (st - st0) & 1;
        if (st < st1) {
            stage(cur ^ 1, st + 1);
            asm volatile("s_waitcnt vmcnt(8)" ::: "memory");
        } else {
            asm volatile("s_waitcnt vmcnt(0)" ::: "memory");
        }
        __builtin_amdgcn_s_barrier();
        __builtin_amdgcn_sched_barrier(0);

        const int s0 = st * 64;
        const float* ap = aa + bhS + s0;
        f32x4 av[4];
        av[0] = *(const f32x4*)&ap[g * 4];
        av[1] = *(const f32x4*)&ap[16 + g * 4];
        av[2] = *(const f32x4*)&ap[32 + g * 4];
        av[3] = *(const f32x4*)&ap[48 + g * 4];

        // ---- QK^T (S^T tiles) ----
        f32x4 stacc[2][4];
        #pragma unroll
        for (int nt = 0; nt < 2; ++nt)
            #pragma unroll
            for (int ct = 0; ct < 4; ++ct)
                stacc[nt][ct] = (f32x4){0.f, 0.f, 0.f, 0.f};
        #pragma unroll
        for (int ct = 0; ct < 4; ++ct) {
            const int row = ct * 16 + l16;
            #pragma unroll
            for (int kb = 0; kb < 4; ++kb) {
                f16x8 kf = *(const f16x8*)((const char*)&kbuf[cur][0] +
                            ((row * 256 + kb * 64 + g * 16) ^ ((row & 7) << 4)));
                stacc[0][ct] = __builtin_amdgcn_mfma_f32_16x16x32_f16(kf, qf[0][kb], stacc[0][ct], 0, 0, 0);
                stacc[1][ct] = __builtin_amdgcn_mfma_f32_16x16x32_f16(kf, qf[1][kb], stacc[1][ct], 0, 0, 0);
            }
        }

        // ---- decay * score, causal mask, denominator partials ----
        const bool diag = (st >= 2 * qq);
        #pragma unroll
        for (int nt = 0; nt < 2; ++nt) {
            float dsum = 0.f;
            const int t_idx = tw0 + nt * 16 + l16;
            #pragma unroll
            for (int ct = 0; ct < 4; ++ct) {
                #pragma unroll
                for (int i = 0; i < 4; ++i) {
                    const float e = K_IS * __expf(cdec[nt] + av[ct][i]);
                    float val = stacc[nt][ct][i] * e;
                    if (diag && (s0 + ct * 16 + g * 4 + i > t_idx)) val = 0.f;
                    dsum += val;
                    stacc[nt][ct][i] = val;
                }
            }
            dpart[nt] += dsum;
        }

        // ---- pack P (lane-local, sigma k-slots) ----
        f16x8 pf[2][2];
        #pragma unroll
        for (int nt = 0; nt < 2; ++nt) {
            #pragma unroll
            for (int kb = 0; kb < 2; ++kb) {
                U8 uu;
                uu.h[0] = __builtin_amdgcn_cvt_pkrtz(stacc[nt][2 * kb][0],     stacc[nt][2 * kb][1]);
                uu.h[1] = __builtin_amdgcn_cvt_pkrtz(stacc[nt][2 * kb][2],     stacc[nt][2 * kb][3]);
                uu.h[2] = __builtin_amdgcn_cvt_pkrtz(stacc[nt][2 * kb + 1][0], stacc[nt][2 * kb + 1][1]);
                uu.h[3] = __builtin_amdgcn_cvt_pkrtz(stacc[nt][2 * kb + 1][2], stacc[nt][2 * kb + 1][3]);
                pf[nt][kb] = uu.v;
            }
        }

        // ---- PV: single b128 V-frag reads (sigma-matched layout) ----
        #pragma unroll
        for (int mt = 0; mt < 8; ++mt) {
            const int dI = mt * 16 + l16;
            #pragma unroll
            for (int kb = 0; kb < 2; ++kb) {
                f16x8 vf = *(const f16x8*)((const char*)&vbuf[cur][0] +
                            dI * 128 + ((kb * 64 + g * 16) ^ ((dI & 7) << 4)));
                oacc[0][mt] = __builtin_amdgcn_mfma_f32_16x16x32_f16(vf, pf[0][kb], oacc[0][mt], 0, 0, 0);
                oacc[1][mt] = __builtin_amdgcn_mfma_f32_16x16x32_f16(vf, pf[1][kb], oacc[1][mt], 0, 0, 0);
            }
        }
        __builtin_amdgcn_sched_barrier(0);
        __builtin_amdgcn_s_barrier();
    }

    // ---- epilogue: coalesced fragment-order partials ----
    const int uoff = (qq < 6) ? qq : ((qq < 12) ? (6 + 2 * (qq - 6)) : (18 + 3 * (qq - 12)));
    const size_t cidx = (size_t)bh * 30 + uoff + chunk;
    #pragma unroll
    for (int nt = 0; nt < 2; ++nt) {
        float den = dpart[nt];
        den += __shfl_xor(den, 16);
        den += __shfl_xor(den, 32);
        const int row = wv * 32 + nt * 16 + l16;
        if (g == 0) pden[cidx * 128 + row] = den;
        #pragma unroll
        for (int mt = 0; mt < 8; ++mt) {
            ushort4 pk;
            pk.x = f2bf(oacc[nt][mt][0]);
            pk.y = f2bf(oacc[nt][mt][1]);
            pk.z = f2bf(oacc[nt][mt][2]);
            pk.w = f2bf(oacc[nt][mt][3]);
            *(ushort4*)&pnum[((cidx * 64 + wv * 16 + nt * 8 + mt) << 8) + lane * 4] = pk;
        }
    }
}

// ---------------- Kernel 5: chunk reduction + denom + RMSNorm ----------------
__global__ __launch_bounds__(256) void reduce_kernel(
    const unsigned short* __restrict__ pnum, const float* __restrict__ pden,
    const float* __restrict__ mstab, const float* __restrict__ onw,
    float* __restrict__ out)
{
    const int id = blockIdx.x;          // 16 bh * 16 qq
    const int bh = id & 15;
    const int qq = id >> 4;
    const int b = bh >> 3, h = bh & 7;
    const int tid = threadIdx.x;
    const int lane = tid & 63;
    const int wv = tid >> 6;
    const int g = lane >> 4;
    const int l16 = lane & 15;

    const int nch = (qq < 6) ? 1 : ((qq < 12) ? 2 : 3);
    const int uoff = (qq < 6) ? qq : ((qq < 12) ? (6 + 2 * (qq - 6)) : (18 + 3 * (qq - 12)));
    const size_t cbase = (size_t)bh * 30 + uoff;

    f32x4 acc[2][8];
    #pragma unroll
    for (int nt = 0; nt < 2; ++nt)
        #pragma unroll
        for (int mt = 0; mt < 8; ++mt)
            acc[nt][mt] = (f32x4){0.f, 0.f, 0.f, 0.f};
    float den[2] = {0.f, 0.f};

    for (int c = 0; c < nch; ++c) {
        const size_t fb = (cbase + c) * 64 + wv * 16;
        #pragma unroll
        for (int nt = 0; nt < 2; ++nt) {
            #pragma unroll
            for (int mt = 0; mt < 8; ++mt) {
                ushort4 t4 = *(const ushort4*)&pnum[((fb + nt * 8 + mt) << 8) + lane * 4];
                acc[nt][mt][0] += bf2f(t4.x);
                acc[nt][mt][1] += bf2f(t4.y);
                acc[nt][mt][2] += bf2f(t4.z);
                acc[nt][mt][3] += bf2f(t4.w);
            }
            den[nt] += pden[(cbase + c) * 128 + wv * 32 + nt * 16 + l16];
        }
    }

    #pragma unroll
    for (int nt = 0; nt < 2; ++nt) {
        const int t = qq * 128 + wv * 32 + nt * 16 + l16;
        const float m = mstab[(size_t)bh * SS + t];
        const float em = __expf(-m);
        const float dt = den[nt] * em;
        const float denf = fmaxf(fabsf(dt), em) + B_EPS;
        const float inv = em / denf;
        float ssq = 0.f;
        #pragma unroll
        for (int mt = 0; mt < 8; ++mt) {
            #pragma unroll
            for (int i = 0; i < 4; ++i) {
                acc[nt][mt][i] *= inv;
                ssq += acc[nt][mt][i] * acc[nt][mt][i];
            }
        }
        ssq += __shfl_xor(ssq, 16);
        ssq += __shfl_xor(ssq, 32);
        const float rms = rsqrtf(ssq * (1.0f / DHH) + N_EPS);

        float* orow = out + ((size_t)b * SS + t) * DIMM + h * DHH;
        #pragma unroll
        for (int mt = 0; mt < 8; ++mt) {
            float4 gn = *(const float4*)&onw[h * DHH + mt * 16 + g * 4];
            float4 o4;
            o4.x = acc[nt][mt][0] * rms * (1.f + gn.x);
            o4.y = acc[nt][mt][1] * rms * (1.f + gn.y);
            o4.z = acc[nt][mt][2] * rms * (1.f + gn.z);
            o4.w = acc[nt][mt][3] * rms * (1.f + gn.w);
            *(float4*)&orow[mt * 16 + g * 4] = o4;
        }
    }
}

extern "C" void kernel_launch(void* const* d_in, const int* in_sizes, int n_in,
                              void* d_out, int out_size, void* d_ws, size_t ws_size,
                              hipStream_t stream) {
    const float* q   = (const float*)d_in[0];
    const float* k   = (const float*)d_in[1];
    const float* v   = (const float*)d_in[2];
    const float* gw  = (const float*)d_in[3];
    const float* gb  = (const float*)d_in[4];
    const float* onw = (const float*)d_in[5];
    float* out = (float*)d_out;

    float* ws    = (float*)d_ws;
    float* i_pre = ws;                  // 32768 f32
    float* lfcs  = ws + 32768;          // 32768
    float* mm    = ws + 65536;          // 32768
    float* aa    = ws + 98304;          // 32768
    float* pden  = ws + 131072;         // 480*128 = 61440 f32
    unsigned short* pnum = (unsigned short*)((char*)d_ws + 1048576);   // 480*32KB = 15728640 B
    unsigned short* k16  = (unsigned short*)((char*)d_ws + 16777216);  // 8388608 B
    unsigned short* v16  = (unsigned short*)((char*)d_ws + 25165824);  // 8388608 B -> end 32MB

    hipLaunchKernelGGL(gate_kernel, dim3(BB * SS / 4), dim3(256), 0, stream,
                       q, k, v, gw, gb, i_pre, lfcs, k16);
    hipLaunchKernelGGL(vprep_kernel, dim3(16 * 32), dim3(128), 0, stream, v, v16);
    hipLaunchKernelGGL(scan_kernel, dim3(BB * NHH), dim3(256), 0, stream, i_pre, lfcs, mm, aa);
    hipLaunchKernelGGL(mlstm_splitk, dim3(480), dim3(256), 0, stream,
                       q, k16, v16, lfcs, aa, pnum, pden);
    hipLaunchKernelGGL(reduce_kernel, dim3(16 * 16), dim3(256), 0, stream,
                       pnum, pden, mm, onw, out);
}

// Round 7
// 84.066 us; speedup vs baseline: 24.7730x; 1.2956x over previous
//
#include <hip/hip_runtime.h>
#include <math.h>

#define BB 2
#define SS 2048
#define DIMM 1024
#define NHH 8
#define DHH 128

constexpr float GATE_CAP = 15.0f;
constexpr float B_EPS = 5e-5f;
constexpr float N_EPS = 1e-6f;
constexpr float K_IS = 0.08838834764831845f; // 1/sqrt(128)

typedef _Float16 f16x8 __attribute__((ext_vector_type(8)));
typedef __fp16  h16x2 __attribute__((ext_vector_type(2)));
typedef float f32x4 __attribute__((ext_vector_type(4)));

union U8 { f16x8 v; h16x2 h[4]; unsigned int u[4]; };

__device__ inline unsigned short f2bf(float x) {
    unsigned u = __builtin_bit_cast(unsigned, x);
    unsigned r = (u + 0x7fff + ((u >> 16) & 1)) >> 16;   // RTNE
    return (unsigned short)r;
}
__device__ inline float bf2f(unsigned short s) {
    unsigned u = ((unsigned)s) << 16;
    return __builtin_bit_cast(float, u);
}

#define GLD_LDS16(gsrc, ldst)                                                   \
    __builtin_amdgcn_global_load_lds(                                           \
        (const __attribute__((address_space(1))) unsigned int*)(gsrc),          \
        (__attribute__((address_space(3))) unsigned int*)(ldst), 16, 0, 0)

// ---------------- Kernel 1: gate GEMV, LDS-staged x, per-wave o-split ----------------
// 512 blocks x 256 thr; 8 rows/block; wave w computes outs 4w..4w+3.
__global__ __launch_bounds__(256) void gate_kernel(
    const float* __restrict__ q, const float* __restrict__ k, const float* __restrict__ v,
    const float* __restrict__ gw, const float* __restrict__ gb,
    float* __restrict__ i_pre, float* __restrict__ lfcs)
{
    __shared__ __align__(16) float xs[2][8][1024];   // 64 KB double-buffered x-slice

    const int tid = threadIdx.x;
    const int lane = tid & 63;
    const int wv = tid >> 6;
    const int bs0 = blockIdx.x * 8;

    const float* srcs[3] = {q, k, v};

    // stage slice i into buf: 8 rows x 4KB, linear GLD (wave-uniform base + lane*16)
    auto stage = [&](int buf, int i) {
        const char* src = (const char*)(srcs[i] + (size_t)bs0 * DIMM);
        #pragma unroll
        for (int j = 0; j < 8; ++j) {
            GLD_LDS16(src + j * 4096 + wv * 1024 + lane * 16,
                      (char*)&xs[buf][j][0] + wv * 1024 + lane * 16);
        }
    };

    float acc[8][4];
    #pragma unroll
    for (int r = 0; r < 8; ++r)
        #pragma unroll
        for (int o = 0; o < 4; ++o) acc[r][o] = 0.f;

    stage(0, 0);

    for (int i = 0; i < 3; ++i) {
        const int cur = i & 1;
        if (i < 2) {
            stage(cur ^ 1, i + 1);
            asm volatile("s_waitcnt vmcnt(8)" ::: "memory");
        } else {
            asm volatile("s_waitcnt vmcnt(0)" ::: "memory");
        }
        __builtin_amdgcn_s_barrier();
        __builtin_amdgcn_sched_barrier(0);

        const float* gwi = gw + (wv * 4) * 3 * DIMM + i * DIMM;
        #pragma unroll
        for (int step = 0; step < 4; ++step) {
            float4 w4[4];
            #pragma unroll
            for (int o = 0; o < 4; ++o)
                w4[o] = *(const float4*)&gwi[o * 3 * DIMM + step * 256 + lane * 4];
            #pragma unroll
            for (int r = 0; r < 8; ++r) {
                const float4 xv = *(const float4*)&xs[cur][r][step * 256 + lane * 4];
                #pragma unroll
                for (int o = 0; o < 4; ++o)
                    acc[r][o] += xv.x * w4[o].x + xv.y * w4[o].y
                               + xv.z * w4[o].z + xv.w * w4[o].w;
            }
        }
        __builtin_amdgcn_s_barrier();   // protect buf before next stage overwrites
    }

    // reduce lanes {l, l^16, l^32, l^48}
    #pragma unroll
    for (int r = 0; r < 8; ++r)
        #pragma unroll
        for (int o = 0; o < 4; ++o) {
            acc[r][o] += __shfl_xor(acc[r][o], 16);
            acc[r][o] += __shfl_xor(acc[r][o], 32);
        }

    // transpose partials via LDS (padded stride 36 to avoid bank conflicts)
    float* scr = &xs[0][0][0];           // reuse (post-barrier)
    const int l16 = lane & 15;
    if (l16 == lane) { // lanes 0..15 of each wave hold the 16 surviving partials
        #pragma unroll
        for (int r = 0; r < 8; ++r) {
            float4 st = {acc[r][0], acc[r][1], acc[r][2], acc[r][3]};
            *(float4*)&scr[wv * 576 + l16 * 36 + r * 4] = st;
        }
    }
    __syncthreads();

    if (tid < 128) {
        const int row = tid & 7, o = tid >> 3;
        const float* base = &scr[(o >> 2) * 576 + row * 4 + (o & 3)];
        float s = 0.f;
        #pragma unroll
        for (int j = 0; j < 16; ++j) s += base[j * 36];
        float p = s + gb[o];
        p = GATE_CAP * tanhf(p / GATE_CAP);
        const int bs = bs0 + row;
        const int b = bs >> 11, s2 = bs & 2047;
        if (o < NHH) {
            i_pre[((size_t)b * NHH + o) * SS + s2] = p;
        } else {
            const int h = o - NHH;
            const float ls = (p >= 0.f) ? -log1pf(expf(-p)) : p - log1pf(expf(p));
            lfcs[((size_t)b * NHH + h) * SS + s2] = ls;
        }
    }
}

// ---------------- Kernel 2: K swizzled-copy + V transpose to f16 ----------------
__global__ __launch_bounds__(256) void prep_kv(
    const float* __restrict__ k, const float* __restrict__ v,
    unsigned short* __restrict__ k16, unsigned short* __restrict__ v16)
{
    const int id = blockIdx.x;       // 16 bh * 32 st
    const int bh = id & 15;
    const int st = id >> 4;
    const int b = bh >> 3, h = bh & 7;
    const int tid = threadIdx.x;

    // ---- K: row-major f16, swizzle baked: byte ^= (s&7)<<4 ----
    {
        const float* kp = k + ((size_t)b * SS + st * 64) * DIMM + h * DHH;
        char* kb_ = (char*)k16 + ((size_t)bh * SS + st * 64) * 256;
        #pragma unroll
        for (int j = 0; j < 8; ++j) {
            const int item = j * 256 + tid;
            const int s = item >> 5, dq = item & 31;
            float4 kx = *(const float4*)&kp[(size_t)s * DIMM + dq * 4];
            h16x2 p0 = __builtin_amdgcn_cvt_pkrtz(kx.x, kx.y);
            h16x2 p1 = __builtin_amdgcn_cvt_pkrtz(kx.z, kx.w);
            uint2 wd;
            wd.x = __builtin_bit_cast(unsigned int, p0);
            wd.y = __builtin_bit_cast(unsigned int, p1);
            *(uint2*)(kb_ + s * 256 + ((dq * 8) ^ ((s & 7) << 4))) = wd;
        }
    }

    // ---- V: sigma-fragment layout (as before) ----
    {
        const int d2 = (tid & 63) * 2;
        const int kb = (tid >> 6) & 1;
        const int gq = tid >> 7;     // 0..1
        const float* vp = v + ((size_t)b * SS + st * 64 + kb * 32) * DIMM + h * DHH + d2;
        char* base = (char*)v16 + ((size_t)bh * 32 + st) * 16384;
        #pragma unroll
        for (int gg = 0; gg < 2; ++gg) {
            const int g = gq * 2 + gg;
            float2 e[8];
            #pragma unroll
            for (int j = 0; j < 8; ++j) {
                const int s = 16 * (j >> 2) + 4 * g + (j & 3);
                e[j] = *(const float2*)&vp[(size_t)s * DIMM];
            }
            U8 u0, u1;
            u0.h[0] = __builtin_amdgcn_cvt_pkrtz(e[0].x, e[1].x);
            u0.h[1] = __builtin_amdgcn_cvt_pkrtz(e[2].x, e[3].x);
            u0.h[2] = __builtin_amdgcn_cvt_pkrtz(e[4].x, e[5].x);
            u0.h[3] = __builtin_amdgcn_cvt_pkrtz(e[6].x, e[7].x);
            u1.h[0] = __builtin_amdgcn_cvt_pkrtz(e[0].y, e[1].y);
            u1.h[1] = __builtin_amdgcn_cvt_pkrtz(e[2].y, e[3].y);
            u1.h[2] = __builtin_amdgcn_cvt_pkrtz(e[4].y, e[5].y);
            u1.h[3] = __builtin_amdgcn_cvt_pkrtz(e[6].y, e[7].y);
            const int p0 = kb * 64 + g * 16;
            *(f16x8*)(base + d2 * 128       + (p0 ^ ((d2 & 7) << 4)))       = u0.v;
            *(f16x8*)(base + (d2 + 1) * 128 + (p0 ^ (((d2 + 1) & 7) << 4))) = u1.v;
        }
    }
}

// ---------------- Kernel 3: block-parallel cumsum + prefix-max ----------------
__global__ __launch_bounds__(256) void scan_kernel(
    const float* __restrict__ i_pre,
    float* __restrict__ lfcs, float* __restrict__ mstab, float* __restrict__ aa)
{
    const int bh = blockIdx.x;
    const int tid = threadIdx.x;
    const int lane = tid & 63, wv = tid >> 6;
    const size_t base = (size_t)bh * SS + tid * 8;

    float x[8];
    {
        float4 a0 = *(const float4*)&lfcs[base];
        float4 a1 = *(const float4*)&lfcs[base + 4];
        x[0] = a0.x; x[1] = a0.y; x[2] = a0.z; x[3] = a0.w;
        x[4] = a1.x; x[5] = a1.y; x[6] = a1.z; x[7] = a1.w;
    }
    #pragma unroll
    for (int i = 1; i < 8; ++i) x[i] += x[i - 1];

    const float tot = x[7];
    float inc = tot;
    #pragma unroll
    for (int off = 1; off < 64; off <<= 1) {
        float n = __shfl_up(inc, off);
        if (lane >= off) inc += n;
    }
    const float exc = inc - tot;

    __shared__ float wt[4], wm[4];
    if (lane == 63) wt[wv] = inc;
    __syncthreads();
    float wpre = 0.f;
    for (int w = 0; w < 4; ++w) if (w < wv) wpre += wt[w];
    const float off0 = exc + wpre;
    #pragma unroll
    for (int i = 0; i < 8; ++i) x[i] += off0;
    {
        float4 s0 = {x[0], x[1], x[2], x[3]}, s1 = {x[4], x[5], x[6], x[7]};
        *(float4*)&lfcs[base] = s0;
        *(float4*)&lfcs[base + 4] = s1;
    }

    float g[8];
    {
        float4 i0 = *(const float4*)&i_pre[base];
        float4 i1 = *(const float4*)&i_pre[base + 4];
        g[0] = i0.x - x[0]; g[1] = i0.y - x[1]; g[2] = i0.z - x[2]; g[3] = i0.w - x[3];
        g[4] = i1.x - x[4]; g[5] = i1.y - x[5]; g[6] = i1.z - x[6]; g[7] = i1.w - x[7];
        float4 s0 = {g[0], g[1], g[2], g[3]}, s1 = {g[4], g[5], g[6], g[7]};
        *(float4*)&aa[base] = s0;
        *(float4*)&aa[base + 4] = s1;
    }
    float mg[8];
    mg[0] = g[0];
    #pragma unroll
    for (int i = 1; i < 8; ++i) mg[i] = fmaxf(mg[i - 1], g[i]);

    float minc = mg[7];
    #pragma unroll
    for (int off = 1; off < 64; off <<= 1) {
        float n = __shfl_up(minc, off);
        if (lane >= off) minc = fmaxf(minc, n);
    }
    float mexc = __shfl_up(minc, 1);
    if (lane == 0) mexc = -1e30f;
    if (lane == 63) wm[wv] = minc;
    __syncthreads();
    float wmpre = -1e30f;
    for (int w = 0; w < 4; ++w) if (w < wv) wmpre = fmaxf(wmpre, wm[w]);
    const float pm = fmaxf(mexc, wmpre);
    float4 s0, s1;
    s0.x = x[0] + fmaxf(pm, mg[0]); s0.y = x[1] + fmaxf(pm, mg[1]);
    s0.z = x[2] + fmaxf(pm, mg[2]); s0.w = x[3] + fmaxf(pm, mg[3]);
    s1.x = x[4] + fmaxf(pm, mg[4]); s1.y = x[5] + fmaxf(pm, mg[5]);
    s1.z = x[6] + fmaxf(pm, mg[6]); s1.w = x[7] + fmaxf(pm, mg[7]);
    *(float4*)&mstab[base] = s0;
    *(float4*)&mstab[base + 4] = s1;
}

// ---------------- Kernel 4: MFMA mLSTM split-K (256 thr, 128 t-rows) ----------------
__global__ __launch_bounds__(256, 2) void mlstm_splitk(
    const float* __restrict__ q,
    const unsigned short* __restrict__ k16, const unsigned short* __restrict__ v16,
    const float* __restrict__ lfcs, const float* __restrict__ aa,
    unsigned short* __restrict__ pnum, float* __restrict__ pden)
{
    __shared__ __align__(16) unsigned short kbuf[2][8192];
    __shared__ __align__(16) unsigned short vbuf[2][8192];

    const int tid = threadIdx.x;
    const int lane = tid & 63;
    const int wv = tid >> 6;
    const int g = lane >> 4;
    const int l16 = lane & 15;

    const int id = blockIdx.x;
    int bh, qq, chunk;
    if (id < 256) {
        bh = id & 15;
        const int j = id >> 4;
        if (j < 7)       { qq = 5 + j;               chunk = 0; }
        else if (j == 7) { qq = 11;                  chunk = 1; }
        else             { qq = 12 + ((j - 8) >> 1); chunk = (j - 8) & 1; }
    } else {
        const int e = id - 256;
        bh = e & 15;
        const int j = e >> 4;
        if (j < 5)       { qq = j;             chunk = 0; }
        else if (j < 10) { qq = 6 + (j - 5);   chunk = 1; }
        else             { qq = 12 + (j - 10); chunk = 2; }
    }
    const int b = bh >> 3, h = bh & 7;
    const int tw0 = qq * 128 + 32 * wv;

    const size_t bhS = (size_t)bh * SS;
    const float* qp = q + (size_t)b * SS * DIMM + h * DHH;
    const char* kg = (const char*)k16 + (size_t)bh * 524288;
    const char* vg = (const char*)v16 + (size_t)bh * 524288;

    f16x8 qf[2][4];
    float cdec[2];
    #pragma unroll
    for (int nt = 0; nt < 2; ++nt) {
        const int t = tw0 + 16 * nt + l16;
        cdec[nt] = lfcs[bhS + t];
        const float* qrow = qp + (size_t)t * DIMM;
        #pragma unroll
        for (int kb = 0; kb < 4; ++kb) {
            float4 x0 = *(const float4*)&qrow[kb * 32 + g * 8];
            float4 x1 = *(const float4*)&qrow[kb * 32 + g * 8 + 4];
            U8 uu;
            uu.h[0] = __builtin_amdgcn_cvt_pkrtz(x0.x, x0.y);
            uu.h[1] = __builtin_amdgcn_cvt_pkrtz(x0.z, x0.w);
            uu.h[2] = __builtin_amdgcn_cvt_pkrtz(x1.x, x1.y);
            uu.h[3] = __builtin_amdgcn_cvt_pkrtz(x1.z, x1.w);
            qf[nt][kb] = uu.v;
        }
    }

    f32x4 oacc[2][8];
    #pragma unroll
    for (int nt = 0; nt < 2; ++nt)
        #pragma unroll
        for (int mt = 0; mt < 8; ++mt)
            oacc[nt][mt] = (f32x4){0.f, 0.f, 0.f, 0.f};
    float dpart[2] = {0.f, 0.f};

    const int st0 = chunk * 12;
    const int st1m = 2 * qq + 1;
    const int st1 = (st0 + 11 < st1m) ? (st0 + 11) : st1m;

    auto stage = [&](int bi, int st) {
        const char* ksrc = kg + (size_t)st * 16384;
        const char* vsrc = vg + (size_t)st * 16384;
        #pragma unroll
        for (int j = 0; j < 4; ++j) {
            const int off = (j * 4 + wv) * 1024;
            GLD_LDS16(ksrc + off + lane * 16, (char*)&kbuf[bi][0] + off);
            GLD_LDS16(vsrc + off + lane * 16, (char*)&vbuf[bi][0] + off);
        }
    };

    stage(0, st0);

    for (int st = st0; st <= st1; ++st) {
        const int cur = (st - st0) & 1;
        if (st < st1) {
            stage(cur ^ 1, st + 1);
            asm volatile("s_waitcnt vmcnt(8)" ::: "memory");
        } else {
            asm volatile("s_waitcnt vmcnt(0)" ::: "memory");
        }
        __builtin_amdgcn_s_barrier();
        __builtin_amdgcn_sched_barrier(0);

        const int s0 = st * 64;
        const float* ap = aa + bhS + s0;
        f32x4 av[4];
        av[0] = *(const f32x4*)&ap[g * 4];
        av[1] = *(const f32x4*)&ap[16 + g * 4];
        av[2] = *(const f32x4*)&ap[32 + g * 4];
        av[3] = *(const f32x4*)&ap[48 + g * 4];

        f32x4 stacc[2][4];
        #pragma unroll
        for (int nt = 0; nt < 2; ++nt)
            #pragma unroll
            for (int ct = 0; ct < 4; ++ct)
                stacc[nt][ct] = (f32x4){0.f, 0.f, 0.f, 0.f};
        #pragma unroll
        for (int ct = 0; ct < 4; ++ct) {
            const int row = ct * 16 + l16;
            #pragma unroll
            for (int kb = 0; kb < 4; ++kb) {
                f16x8 kf = *(const f16x8*)((const char*)&kbuf[cur][0] +
                            ((row * 256 + kb * 64 + g * 16) ^ ((row & 7) << 4)));
                stacc[0][ct] = __builtin_amdgcn_mfma_f32_16x16x32_f16(kf, qf[0][kb], stacc[0][ct], 0, 0, 0);
                stacc[1][ct] = __builtin_amdgcn_mfma_f32_16x16x32_f16(kf, qf[1][kb], stacc[1][ct], 0, 0, 0);
            }
        }

        const bool diag = (st >= 2 * qq);
        #pragma unroll
        for (int nt = 0; nt < 2; ++nt) {
            float dsum = 0.f;
            const int t_idx = tw0 + nt * 16 + l16;
            #pragma unroll
            for (int ct = 0; ct < 4; ++ct) {
                #pragma unroll
                for (int i = 0; i < 4; ++i) {
                    const float e = K_IS * __expf(cdec[nt] + av[ct][i]);
                    float val = stacc[nt][ct][i] * e;
                    if (diag && (s0 + ct * 16 + g * 4 + i > t_idx)) val = 0.f;
                    dsum += val;
                    stacc[nt][ct][i] = val;
                }
            }
            dpart[nt] += dsum;
        }

        f16x8 pf[2][2];
        #pragma unroll
        for (int nt = 0; nt < 2; ++nt) {
            #pragma unroll
            for (int kb = 0; kb < 2; ++kb) {
                U8 uu;
                uu.h[0] = __builtin_amdgcn_cvt_pkrtz(stacc[nt][2 * kb][0],     stacc[nt][2 * kb][1]);
                uu.h[1] = __builtin_amdgcn_cvt_pkrtz(stacc[nt][2 * kb][2],     stacc[nt][2 * kb][3]);
                uu.h[2] = __builtin_amdgcn_cvt_pkrtz(stacc[nt][2 * kb + 1][0], stacc[nt][2 * kb + 1][1]);
                uu.h[3] = __builtin_amdgcn_cvt_pkrtz(stacc[nt][2 * kb + 1][2], stacc[nt][2 * kb + 1][3]);
                pf[nt][kb] = uu.v;
            }
        }

        #pragma unroll
        for (int mt = 0; mt < 8; ++mt) {
            const int dI = mt * 16 + l16;
            #pragma unroll
            for (int kb = 0; kb < 2; ++kb) {
                f16x8 vf = *(const f16x8*)((const char*)&vbuf[cur][0] +
                            dI * 128 + ((kb * 64 + g * 16) ^ ((dI & 7) << 4)));
                oacc[0][mt] = __builtin_amdgcn_mfma_f32_16x16x32_f16(vf, pf[0][kb], oacc[0][mt], 0, 0, 0);
                oacc[1][mt] = __builtin_amdgcn_mfma_f32_16x16x32_f16(vf, pf[1][kb], oacc[1][mt], 0, 0, 0);
            }
        }
        __builtin_amdgcn_sched_barrier(0);
        __builtin_amdgcn_s_barrier();
    }

    const int uoff = (qq < 6) ? qq : ((qq < 12) ? (6 + 2 * (qq - 6)) : (18 + 3 * (qq - 12)));
    const size_t cidx = (size_t)bh * 30 + uoff + chunk;
    #pragma unroll
    for (int nt = 0; nt < 2; ++nt) {
        float den = dpart[nt];
        den += __shfl_xor(den, 16);
        den += __shfl_xor(den, 32);
        const int row = wv * 32 + nt * 16 + l16;
        if (g == 0) pden[cidx * 128 + row] = den;
        #pragma unroll
        for (int mt = 0; mt < 8; ++mt) {
            ushort4 pk;
            pk.x = f2bf(oacc[nt][mt][0]);
            pk.y = f2bf(oacc[nt][mt][1]);
            pk.z = f2bf(oacc[nt][mt][2]);
            pk.w = f2bf(oacc[nt][mt][3]);
            *(ushort4*)&pnum[((cidx * 64 + wv * 16 + nt * 8 + mt) << 8) + lane * 4] = pk;
        }
    }
}

// ---------------- Kernel 5: chunk reduction + denom + RMSNorm ----------------
__global__ __launch_bounds__(256) void reduce_kernel(
    const unsigned short* __restrict__ pnum, const float* __restrict__ pden,
    const float* __restrict__ mstab, const float* __restrict__ onw,
    float* __restrict__ out)
{
    const int id = blockIdx.x;
    const int bh = id & 15;
    const int qq = id >> 4;
    const int b = bh >> 3, h = bh & 7;
    const int tid = threadIdx.x;
    const int lane = tid & 63;
    const int wv = tid >> 6;
    const int g = lane >> 4;
    const int l16 = lane & 15;

    const int nch = (qq < 6) ? 1 : ((qq < 12) ? 2 : 3);
    const int uoff = (qq < 6) ? qq : ((qq < 12) ? (6 + 2 * (qq - 6)) : (18 + 3 * (qq - 12)));
    const size_t cbase = (size_t)bh * 30 + uoff;

    f32x4 acc[2][8];
    #pragma unroll
    for (int nt = 0; nt < 2; ++nt)
        #pragma unroll
        for (int mt = 0; mt < 8; ++mt)
            acc[nt][mt] = (f32x4){0.f, 0.f, 0.f, 0.f};
    float den[2] = {0.f, 0.f};

    for (int c = 0; c < nch; ++c) {
        const size_t fb = (cbase + c) * 64 + wv * 16;
        #pragma unroll
        for (int nt = 0; nt < 2; ++nt) {
            #pragma unroll
            for (int mt = 0; mt < 8; ++mt) {
                ushort4 t4 = *(const ushort4*)&pnum[((fb + nt * 8 + mt) << 8) + lane * 4];
                acc[nt][mt][0] += bf2f(t4.x);
                acc[nt][mt][1] += bf2f(t4.y);
                acc[nt][mt][2] += bf2f(t4.z);
                acc[nt][mt][3] += bf2f(t4.w);
            }
            den[nt] += pden[(cbase + c) * 128 + wv * 32 + nt * 16 + l16];
        }
    }

    #pragma unroll
    for (int nt = 0; nt < 2; ++nt) {
        const int t = qq * 128 + wv * 32 + nt * 16 + l16;
        const float m = mstab[(size_t)bh * SS + t];
        const float em = __expf(-m);
        const float dt = den[nt] * em;
        const float denf = fmaxf(fabsf(dt), em) + B_EPS;
        const float inv = em / denf;
        float ssq = 0.f;
        #pragma unroll
        for (int mt = 0; mt < 8; ++mt) {
            #pragma unroll
            for (int i = 0; i < 4; ++i) {
                acc[nt][mt][i] *= inv;
                ssq += acc[nt][mt][i] * acc[nt][mt][i];
            }
        }
        ssq += __shfl_xor(ssq, 16);
        ssq += __shfl_xor(ssq, 32);
        const float rms = rsqrtf(ssq * (1.0f / DHH) + N_EPS);

        float* orow = out + ((size_t)b * SS + t) * DIMM + h * DHH;
        #pragma unroll
        for (int mt = 0; mt < 8; ++mt) {
            float4 gn = *(const float4*)&onw[h * DHH + mt * 16 + g * 4];
            float4 o4;
            o4.x = acc[nt][mt][0] * rms * (1.f + gn.x);
            o4.y = acc[nt][mt][1] * rms * (1.f + gn.y);
            o4.z = acc[nt][mt][2] * rms * (1.f + gn.z);
            o4.w = acc[nt][mt][3] * rms * (1.f + gn.w);
            *(float4*)&orow[mt * 16 + g * 4] = o4;
        }
    }
}

extern "C" void kernel_launch(void* const* d_in, const int* in_sizes, int n_in,
                              void* d_out, int out_size, void* d_ws, size_t ws_size,
                              hipStream_t stream) {
    const float* q   = (const float*)d_in[0];
    const float* k   = (const float*)d_in[1];
    const float* v   = (const float*)d_in[2];
    const float* gw  = (const float*)d_in[3];
    const float* gb  = (const float*)d_in[4];
    const float* onw = (const float*)d_in[5];
    float* out = (float*)d_out;

    float* ws    = (float*)d_ws;
    float* i_pre = ws;                  // 32768 f32
    float* lfcs  = ws + 32768;          // 32768
    float* mm    = ws + 65536;          // 32768
    float* aa    = ws + 98304;          // 32768
    float* pden  = ws + 131072;         // 480*128 f32
    unsigned short* pnum = (unsigned short*)((char*)d_ws + 1048576);   // 15728640 B
    unsigned short* k16  = (unsigned short*)((char*)d_ws + 16777216);  // 8388608 B
    unsigned short* v16  = (unsigned short*)((char*)d_ws + 25165824);  // 8388608 B

    hipLaunchKernelGGL(gate_kernel, dim3(BB * SS / 8), dim3(256), 0, stream,
                       q, k, v, gw, gb, i_pre, lfcs);
    hipLaunchKernelGGL(prep_kv, dim3(16 * 32), dim3(256), 0, stream, k, v, k16, v16);
    hipLaunchKernelGGL(scan_kernel, dim3(BB * NHH), dim3(256), 0, stream, i_pre, lfcs, mm, aa);
    hipLaunchKernelGGL(mlstm_splitk, dim3(480), dim3(256), 0, stream,
                       q, k16, v16, lfcs, aa, pnum, pden);
    hipLaunchKernelGGL(reduce_kernel, dim3(16 * 16), dim3(256), 0, stream,
                       pnum, pden, mm, onw, out);
}

// Round 8
// 80.347 us; speedup vs baseline: 25.9197x; 1.0463x over previous
//
#include <hip/hip_runtime.h>
#include <math.h>

#define BB 2
#define SS 2048
#define DIMM 1024
#define NHH 8
#define DHH 128

constexpr float GATE_CAP = 15.0f;
constexpr float B_EPS = 5e-5f;
constexpr float N_EPS = 1e-6f;
constexpr float LOG2E = 1.4426950408889634f;
constexpr float LN_KIS = -2.4260151319598084f;   // ln(1/sqrt(128))

typedef _Float16 f16x8 __attribute__((ext_vector_type(8)));
typedef __fp16  h16x2 __attribute__((ext_vector_type(2)));
typedef float f32x4 __attribute__((ext_vector_type(4)));

union U8 { f16x8 v; h16x2 h[4]; unsigned int u[4]; };

__device__ inline unsigned short f2bf(float x) {
    unsigned u = __builtin_bit_cast(unsigned, x);
    unsigned r = (u + 0x7fff + ((u >> 16) & 1)) >> 16;   // RTNE
    return (unsigned short)r;
}
__device__ inline float bf2f(unsigned short s) {
    unsigned u = ((unsigned)s) << 16;
    return __builtin_bit_cast(float, u);
}

#define GLD_LDS16(gsrc, ldst)                                                   \
    __builtin_amdgcn_global_load_lds(                                           \
        (const __attribute__((address_space(1))) unsigned int*)(gsrc),          \
        (__attribute__((address_space(3))) unsigned int*)(ldst), 16, 0, 0)

// ---------------- Kernel 1: gate GEMV ----------------
// w4 preloaded to regs BEFORE stage-issue so vmcnt(8) never drains the prefetch.
__global__ __launch_bounds__(256) void gate_kernel(
    const float* __restrict__ q, const float* __restrict__ k, const float* __restrict__ v,
    const float* __restrict__ gw, const float* __restrict__ gb,
    float* __restrict__ i_pre, float* __restrict__ lfcs)
{
    __shared__ __align__(16) float xs[2][8][1024];   // 64 KB double-buffered x-slice

    const int tid = threadIdx.x;
    const int lane = tid & 63;
    const int wv = tid >> 6;
    const int bs0 = blockIdx.x * 8;

    const float* srcs[3] = {q, k, v};

    auto stage = [&](int buf, int i) {
        const char* src = (const char*)(srcs[i] + (size_t)bs0 * DIMM);
        #pragma unroll
        for (int j = 0; j < 8; ++j) {
            GLD_LDS16(src + j * 4096 + wv * 1024 + lane * 16,
                      (char*)&xs[buf][j][0] + wv * 1024 + lane * 16);
        }
    };

    float acc[8][4];
    #pragma unroll
    for (int r = 0; r < 8; ++r)
        #pragma unroll
        for (int o = 0; o < 4; ++o) acc[r][o] = 0.f;

    stage(0, 0);

    for (int i = 0; i < 3; ++i) {
        const int cur = i & 1;
        // preload gw slice for this i BEFORE issuing next stage
        const float* gwi = gw + (wv * 4) * 3 * DIMM + i * DIMM;
        float4 w4[4][4];
        #pragma unroll
        for (int step = 0; step < 4; ++step)
            #pragma unroll
            for (int o = 0; o < 4; ++o)
                w4[step][o] = *(const float4*)&gwi[o * 3 * DIMM + step * 256 + lane * 4];

        if (i < 2) {
            stage(cur ^ 1, i + 1);
            asm volatile("s_waitcnt vmcnt(8)" ::: "memory");
        } else {
            asm volatile("s_waitcnt vmcnt(0)" ::: "memory");
        }
        __builtin_amdgcn_s_barrier();
        __builtin_amdgcn_sched_barrier(0);

        #pragma unroll
        for (int step = 0; step < 4; ++step) {
            #pragma unroll
            for (int r = 0; r < 8; ++r) {
                const float4 xv = *(const float4*)&xs[cur][r][step * 256 + lane * 4];
                #pragma unroll
                for (int o = 0; o < 4; ++o)
                    acc[r][o] += xv.x * w4[step][o].x + xv.y * w4[step][o].y
                               + xv.z * w4[step][o].z + xv.w * w4[step][o].w;
            }
        }
        __builtin_amdgcn_s_barrier();
    }

    #pragma unroll
    for (int r = 0; r < 8; ++r)
        #pragma unroll
        for (int o = 0; o < 4; ++o) {
            acc[r][o] += __shfl_xor(acc[r][o], 16);
            acc[r][o] += __shfl_xor(acc[r][o], 32);
        }

    float* scr = &xs[0][0][0];
    const int l16 = lane & 15;
    if (l16 == lane) {
        #pragma unroll
        for (int r = 0; r < 8; ++r) {
            float4 st = {acc[r][0], acc[r][1], acc[r][2], acc[r][3]};
            *(float4*)&scr[wv * 576 + l16 * 36 + r * 4] = st;
        }
    }
    __syncthreads();

    if (tid < 128) {
        const int row = tid & 7, o = tid >> 3;
        const float* base = &scr[(o >> 2) * 576 + row * 4 + (o & 3)];
        float s = 0.f;
        #pragma unroll
        for (int j = 0; j < 16; ++j) s += base[j * 36];
        float p = s + gb[o];
        p = GATE_CAP * tanhf(p / GATE_CAP);
        const int bs = bs0 + row;
        const int b = bs >> 11, s2 = bs & 2047;
        if (o < NHH) {
            i_pre[((size_t)b * NHH + o) * SS + s2] = p;
        } else {
            const int h = o - NHH;
            const float ls = (p >= 0.f) ? -log1pf(expf(-p)) : p - log1pf(expf(p));
            lfcs[((size_t)b * NHH + h) * SS + s2] = ls;
        }
    }
}

// ---------------- Kernel 2: fused prep (K/V f16 layouts) + scan ----------------
// blocks 0..511: prep_kv role; blocks 512..527: scan role (independent work).
__global__ __launch_bounds__(256) void prep_scan(
    const float* __restrict__ k, const float* __restrict__ v,
    unsigned short* __restrict__ k16, unsigned short* __restrict__ v16,
    const float* __restrict__ i_pre,
    float* __restrict__ lfcs, float* __restrict__ mstab, float* __restrict__ aa)
{
    const int id = blockIdx.x;
    const int tid = threadIdx.x;
    __shared__ float wt[4], wm[4];

    if (id < 512) {
        const int bh = id & 15;
        const int st = id >> 4;
        const int b = bh >> 3, h = bh & 7;

        // K: row-major f16, swizzle baked: byte ^= (s&7)<<4
        {
            const float* kp = k + ((size_t)b * SS + st * 64) * DIMM + h * DHH;
            char* kb_ = (char*)k16 + ((size_t)bh * SS + st * 64) * 256;
            #pragma unroll
            for (int j = 0; j < 8; ++j) {
                const int item = j * 256 + tid;
                const int s = item >> 5, dq = item & 31;
                float4 kx = *(const float4*)&kp[(size_t)s * DIMM + dq * 4];
                h16x2 p0 = __builtin_amdgcn_cvt_pkrtz(kx.x, kx.y);
                h16x2 p1 = __builtin_amdgcn_cvt_pkrtz(kx.z, kx.w);
                uint2 wd;
                wd.x = __builtin_bit_cast(unsigned int, p0);
                wd.y = __builtin_bit_cast(unsigned int, p1);
                *(uint2*)(kb_ + s * 256 + ((dq * 8) ^ ((s & 7) << 4))) = wd;
            }
        }
        // V: sigma-fragment layout
        {
            const int d2 = (tid & 63) * 2;
            const int kb = (tid >> 6) & 1;
            const int gq = tid >> 7;
            const float* vp = v + ((size_t)b * SS + st * 64 + kb * 32) * DIMM + h * DHH + d2;
            char* base = (char*)v16 + ((size_t)bh * 32 + st) * 16384;
            #pragma unroll
            for (int gg = 0; gg < 2; ++gg) {
                const int g = gq * 2 + gg;
                float2 e[8];
                #pragma unroll
                for (int j = 0; j < 8; ++j) {
                    const int s = 16 * (j >> 2) + 4 * g + (j & 3);
                    e[j] = *(const float2*)&vp[(size_t)s * DIMM];
                }
                U8 u0, u1;
                u0.h[0] = __builtin_amdgcn_cvt_pkrtz(e[0].x, e[1].x);
                u0.h[1] = __builtin_amdgcn_cvt_pkrtz(e[2].x, e[3].x);
                u0.h[2] = __builtin_amdgcn_cvt_pkrtz(e[4].x, e[5].x);
                u0.h[3] = __builtin_amdgcn_cvt_pkrtz(e[6].x, e[7].x);
                u1.h[0] = __builtin_amdgcn_cvt_pkrtz(e[0].y, e[1].y);
                u1.h[1] = __builtin_amdgcn_cvt_pkrtz(e[2].y, e[3].y);
                u1.h[2] = __builtin_amdgcn_cvt_pkrtz(e[4].y, e[5].y);
                u1.h[3] = __builtin_amdgcn_cvt_pkrtz(e[6].y, e[7].y);
                const int p0 = kb * 64 + g * 16;
                *(f16x8*)(base + d2 * 128       + (p0 ^ ((d2 & 7) << 4)))       = u0.v;
                *(f16x8*)(base + (d2 + 1) * 128 + (p0 ^ (((d2 + 1) & 7) << 4))) = u1.v;
            }
        }
        return;
    }

    // ---- scan role ----
    const int bh = id - 512;
    const int lane = tid & 63, wv = tid >> 6;
    const size_t base = (size_t)bh * SS + tid * 8;

    float x[8];
    {
        float4 a0 = *(const float4*)&lfcs[base];
        float4 a1 = *(const float4*)&lfcs[base + 4];
        x[0] = a0.x; x[1] = a0.y; x[2] = a0.z; x[3] = a0.w;
        x[4] = a1.x; x[5] = a1.y; x[6] = a1.z; x[7] = a1.w;
    }
    #pragma unroll
    for (int i = 1; i < 8; ++i) x[i] += x[i - 1];

    const float tot = x[7];
    float inc = tot;
    #pragma unroll
    for (int off = 1; off < 64; off <<= 1) {
        float n = __shfl_up(inc, off);
        if (lane >= off) inc += n;
    }
    const float exc = inc - tot;

    if (lane == 63) wt[wv] = inc;
    __syncthreads();
    float wpre = 0.f;
    for (int w = 0; w < 4; ++w) if (w < wv) wpre += wt[w];
    const float off0 = exc + wpre;
    #pragma unroll
    for (int i = 0; i < 8; ++i) x[i] += off0;
    {
        float4 s0 = {x[0], x[1], x[2], x[3]}, s1 = {x[4], x[5], x[6], x[7]};
        *(float4*)&lfcs[base] = s0;
        *(float4*)&lfcs[base + 4] = s1;
    }

    float g[8];
    {
        float4 i0 = *(const float4*)&i_pre[base];
        float4 i1 = *(const float4*)&i_pre[base + 4];
        g[0] = i0.x - x[0]; g[1] = i0.y - x[1]; g[2] = i0.z - x[2]; g[3] = i0.w - x[3];
        g[4] = i1.x - x[4]; g[5] = i1.y - x[5]; g[6] = i1.z - x[6]; g[7] = i1.w - x[7];
        // store aa pre-scaled by log2(e) for exp2-based decay
        float4 s0 = {g[0] * LOG2E, g[1] * LOG2E, g[2] * LOG2E, g[3] * LOG2E};
        float4 s1 = {g[4] * LOG2E, g[5] * LOG2E, g[6] * LOG2E, g[7] * LOG2E};
        *(float4*)&aa[base] = s0;
        *(float4*)&aa[base + 4] = s1;
    }
    float mg[8];
    mg[0] = g[0];
    #pragma unroll
    for (int i = 1; i < 8; ++i) mg[i] = fmaxf(mg[i - 1], g[i]);

    float minc = mg[7];
    #pragma unroll
    for (int off = 1; off < 64; off <<= 1) {
        float n = __shfl_up(minc, off);
        if (lane >= off) minc = fmaxf(minc, n);
    }
    float mexc = __shfl_up(minc, 1);
    if (lane == 0) mexc = -1e30f;
    if (lane == 63) wm[wv] = minc;
    __syncthreads();
    float wmpre = -1e30f;
    for (int w = 0; w < 4; ++w) if (w < wv) wmpre = fmaxf(wmpre, wm[w]);
    const float pm = fmaxf(mexc, wmpre);
    float4 s0, s1;
    s0.x = x[0] + fmaxf(pm, mg[0]); s0.y = x[1] + fmaxf(pm, mg[1]);
    s0.z = x[2] + fmaxf(pm, mg[2]); s0.w = x[3] + fmaxf(pm, mg[3]);
    s1.x = x[4] + fmaxf(pm, mg[4]); s1.y = x[5] + fmaxf(pm, mg[5]);
    s1.z = x[6] + fmaxf(pm, mg[6]); s1.w = x[7] + fmaxf(pm, mg[7]);
    *(float4*)&mstab[base] = s0;
    *(float4*)&mstab[base + 4] = s1;
}

// ---------------- Kernel 3: MFMA mLSTM split-K ----------------
// av preloaded before stage-issue; exp2-folded decay; phase-interleaved; setprio.
__global__ __launch_bounds__(256, 2) void mlstm_splitk(
    const float* __restrict__ q,
    const unsigned short* __restrict__ k16, const unsigned short* __restrict__ v16,
    const float* __restrict__ lfcs, const float* __restrict__ aa,
    unsigned short* __restrict__ pnum, float* __restrict__ pden)
{
    __shared__ __align__(16) unsigned short kbuf[2][8192];
    __shared__ __align__(16) unsigned short vbuf[2][8192];

    const int tid = threadIdx.x;
    const int lane = tid & 63;
    const int wv = tid >> 6;
    const int g = lane >> 4;
    const int l16 = lane & 15;

    const int id = blockIdx.x;
    int bh, qq, chunk;
    if (id < 256) {
        bh = id & 15;
        const int j = id >> 4;
        if (j < 7)       { qq = 5 + j;               chunk = 0; }
        else if (j == 7) { qq = 11;                  chunk = 1; }
        else             { qq = 12 + ((j - 8) >> 1); chunk = (j - 8) & 1; }
    } else {
        const int e = id - 256;
        bh = e & 15;
        const int j = e >> 4;
        if (j < 5)       { qq = j;             chunk = 0; }
        else if (j < 10) { qq = 6 + (j - 5);   chunk = 1; }
        else             { qq = 12 + (j - 10); chunk = 2; }
    }
    const int b = bh >> 3, h = bh & 7;
    const int tw0 = qq * 128 + 32 * wv;

    const size_t bhS = (size_t)bh * SS;
    const float* qp = q + (size_t)b * SS * DIMM + h * DHH;
    const char* kg = (const char*)k16 + (size_t)bh * 524288;
    const char* vg = (const char*)v16 + (size_t)bh * 524288;

    f16x8 qf[2][4];
    float cdec2[2];
    #pragma unroll
    for (int nt = 0; nt < 2; ++nt) {
        const int t = tw0 + 16 * nt + l16;
        cdec2[nt] = (lfcs[bhS + t] + LN_KIS) * LOG2E;
        const float* qrow = qp + (size_t)t * DIMM;
        #pragma unroll
        for (int kb = 0; kb < 4; ++kb) {
            float4 x0 = *(const float4*)&qrow[kb * 32 + g * 8];
            float4 x1 = *(const float4*)&qrow[kb * 32 + g * 8 + 4];
            U8 uu;
            uu.h[0] = __builtin_amdgcn_cvt_pkrtz(x0.x, x0.y);
            uu.h[1] = __builtin_amdgcn_cvt_pkrtz(x0.z, x0.w);
            uu.h[2] = __builtin_amdgcn_cvt_pkrtz(x1.x, x1.y);
            uu.h[3] = __builtin_amdgcn_cvt_pkrtz(x1.z, x1.w);
            qf[nt][kb] = uu.v;
        }
    }

    f32x4 oacc[2][8];
    #pragma unroll
    for (int nt = 0; nt < 2; ++nt)
        #pragma unroll
        for (int mt = 0; mt < 8; ++mt)
            oacc[nt][mt] = (f32x4){0.f, 0.f, 0.f, 0.f};
    float dpart[2] = {0.f, 0.f};

    const int st0 = chunk * 12;
    const int st1m = 2 * qq + 1;
    const int st1 = (st0 + 11 < st1m) ? (st0 + 11) : st1m;

    auto stage = [&](int bi, int st) {
        const char* ksrc = kg + (size_t)st * 16384;
        const char* vsrc = vg + (size_t)st * 16384;
        #pragma unroll
        for (int j = 0; j < 4; ++j) {
            const int off = (j * 4 + wv) * 1024;
            GLD_LDS16(ksrc + off + lane * 16, (char*)&kbuf[bi][0] + off);
            GLD_LDS16(vsrc + off + lane * 16, (char*)&vbuf[bi][0] + off);
        }
    };

    stage(0, st0);

    for (int st = st0; st <= st1; ++st) {
        const int cur = (st - st0) & 1;
        // av preload FIRST (older than stage loads -> vmcnt(8) retires them)
        const float* ap = aa + bhS + st * 64;
        f32x4 av[4];
        av[0] = *(const f32x4*)&ap[g * 4];
        av[1] = *(const f32x4*)&ap[16 + g * 4];
        av[2] = *(const f32x4*)&ap[32 + g * 4];
        av[3] = *(const f32x4*)&ap[48 + g * 4];

        if (st < st1) {
            stage(cur ^ 1, st + 1);
            asm volatile("s_waitcnt vmcnt(8)" ::: "memory");
        } else {
            asm volatile("s_waitcnt vmcnt(0)" ::: "memory");
        }
        __builtin_amdgcn_s_barrier();
        __builtin_amdgcn_sched_barrier(0);

        const int s0 = st * 64;
        const bool diag = (st >= 2 * qq);

        f32x4 stacc[2][4];
        #pragma unroll
        for (int nt = 0; nt < 2; ++nt)
            #pragma unroll
            for (int ct = 0; ct < 4; ++ct)
                stacc[nt][ct] = (f32x4){0.f, 0.f, 0.f, 0.f};

        f16x8 pf[2][2];

        // helper macros expanded inline: QKT pair, decay+pack, PV half
        #define QKT_PAIR(CT0)                                                            \
            __builtin_amdgcn_s_setprio(1);                                               \
            _Pragma("unroll")                                                            \
            for (int ct = CT0; ct < CT0 + 2; ++ct) {                                     \
                const int row = ct * 16 + l16;                                           \
                _Pragma("unroll")                                                        \
                for (int kb = 0; kb < 4; ++kb) {                                         \
                    f16x8 kf = *(const f16x8*)((const char*)&kbuf[cur][0] +              \
                                ((row * 256 + kb * 64 + g * 16) ^ ((row & 7) << 4)));    \
                    stacc[0][ct] = __builtin_amdgcn_mfma_f32_16x16x32_f16(kf, qf[0][kb], stacc[0][ct], 0, 0, 0); \
                    stacc[1][ct] = __builtin_amdgcn_mfma_f32_16x16x32_f16(kf, qf[1][kb], stacc[1][ct], 0, 0, 0); \
                }                                                                        \
            }                                                                            \
            __builtin_amdgcn_s_setprio(0);

        #define DECAY_PACK(KB)                                                           \
            _Pragma("unroll")                                                            \
            for (int nt = 0; nt < 2; ++nt) {                                             \
                float dsum = 0.f;                                                        \
                const int t_idx = tw0 + nt * 16 + l16;                                   \
                _Pragma("unroll")                                                        \
                for (int ct = 2 * (KB); ct < 2 * (KB) + 2; ++ct) {                       \
                    _Pragma("unroll")                                                    \
                    for (int i = 0; i < 4; ++i) {                                        \
                        const float e = __builtin_amdgcn_exp2f(cdec2[nt] + av[ct][i]);   \
                        float val = stacc[nt][ct][i] * e;                                \
                        if (diag && (s0 + ct * 16 + g * 4 + i > t_idx)) val = 0.f;       \
                        dsum += val;                                                     \
                        stacc[nt][ct][i] = val;                                          \
                    }                                                                    \
                }                                                                        \
                dpart[nt] += dsum;                                                       \
                U8 uu;                                                                   \
                uu.h[0] = __builtin_amdgcn_cvt_pkrtz(stacc[nt][2*(KB)][0],   stacc[nt][2*(KB)][1]);   \
                uu.h[1] = __builtin_amdgcn_cvt_pkrtz(stacc[nt][2*(KB)][2],   stacc[nt][2*(KB)][3]);   \
                uu.h[2] = __builtin_amdgcn_cvt_pkrtz(stacc[nt][2*(KB)+1][0], stacc[nt][2*(KB)+1][1]); \
                uu.h[3] = __builtin_amdgcn_cvt_pkrtz(stacc[nt][2*(KB)+1][2], stacc[nt][2*(KB)+1][3]); \
                pf[nt][KB] = uu.v;                                                       \
            }

        #define PV_HALF(KB)                                                              \
            __builtin_amdgcn_s_setprio(1);                                               \
            _Pragma("unroll")                                                            \
            for (int mt = 0; mt < 8; ++mt) {                                             \
                const int dI = mt * 16 + l16;                                            \
                f16x8 vf = *(const f16x8*)((const char*)&vbuf[cur][0] +                  \
                            dI * 128 + (((KB) * 64 + g * 16) ^ ((dI & 7) << 4)));        \
                oacc[0][mt] = __builtin_amdgcn_mfma_f32_16x16x32_f16(vf, pf[0][KB], oacc[0][mt], 0, 0, 0); \
                oacc[1][mt] = __builtin_amdgcn_mfma_f32_16x16x32_f16(vf, pf[1][KB], oacc[1][mt], 0, 0, 0); \
            }                                                                            \
            __builtin_amdgcn_s_setprio(0);

        QKT_PAIR(0)
        DECAY_PACK(0)
        QKT_PAIR(2)
        PV_HALF(0)
        DECAY_PACK(1)
        PV_HALF(1)

        #undef QKT_PAIR
        #undef DECAY_PACK
        #undef PV_HALF

        __builtin_amdgcn_sched_barrier(0);
        __builtin_amdgcn_s_barrier();
    }

    const int uoff = (qq < 6) ? qq : ((qq < 12) ? (6 + 2 * (qq - 6)) : (18 + 3 * (qq - 12)));
    const size_t cidx = (size_t)bh * 30 + uoff + chunk;
    #pragma unroll
    for (int nt = 0; nt < 2; ++nt) {
        float den = dpart[nt];
        den += __shfl_xor(den, 16);
        den += __shfl_xor(den, 32);
        const int row = wv * 32 + nt * 16 + l16;
        if (g == 0) pden[cidx * 128 + row] = den;
        #pragma unroll
        for (int mt = 0; mt < 8; ++mt) {
            ushort4 pk;
            pk.x = f2bf(oacc[nt][mt][0]);
            pk.y = f2bf(oacc[nt][mt][1]);
            pk.z = f2bf(oacc[nt][mt][2]);
            pk.w = f2bf(oacc[nt][mt][3]);
            *(ushort4*)&pnum[((cidx * 64 + wv * 16 + nt * 8 + mt) << 8) + lane * 4] = pk;
        }
    }
}

// ---------------- Kernel 4: chunk reduction + denom + RMSNorm ----------------
__global__ __launch_bounds__(256) void reduce_kernel(
    const unsigned short* __restrict__ pnum, const float* __restrict__ pden,
    const float* __restrict__ mstab, const float* __restrict__ onw,
    float* __restrict__ out)
{
    const int id = blockIdx.x;
    const int bh = id & 15;
    const int qq = id >> 4;
    const int b = bh >> 3, h = bh & 7;
    const int tid = threadIdx.x;
    const int lane = tid & 63;
    const int wv = tid >> 6;
    const int g = lane >> 4;
    const int l16 = lane & 15;

    const int nch = (qq < 6) ? 1 : ((qq < 12) ? 2 : 3);
    const int uoff = (qq < 6) ? qq : ((qq < 12) ? (6 + 2 * (qq - 6)) : (18 + 3 * (qq - 12)));
    const size_t cbase = (size_t)bh * 30 + uoff;

    f32x4 acc[2][8];
    #pragma unroll
    for (int nt = 0; nt < 2; ++nt)
        #pragma unroll
        for (int mt = 0; mt < 8; ++mt)
            acc[nt][mt] = (f32x4){0.f, 0.f, 0.f, 0.f};
    float den[2] = {0.f, 0.f};

    for (int c = 0; c < nch; ++c) {
        const size_t fb = (cbase + c) * 64 + wv * 16;
        #pragma unroll
        for (int nt = 0; nt < 2; ++nt) {
            #pragma unroll
            for (int mt = 0; mt < 8; ++mt) {
                ushort4 t4 = *(const ushort4*)&pnum[((fb + nt * 8 + mt) << 8) + lane * 4];
                acc[nt][mt][0] += bf2f(t4.x);
                acc[nt][mt][1] += bf2f(t4.y);
                acc[nt][mt][2] += bf2f(t4.z);
                acc[nt][mt][3] += bf2f(t4.w);
            }
            den[nt] += pden[(cbase + c) * 128 + wv * 32 + nt * 16 + l16];
        }
    }

    #pragma unroll
    for (int nt = 0; nt < 2; ++nt) {
        const int t = qq * 128 + wv * 32 + nt * 16 + l16;
        const float m = mstab[(size_t)bh * SS + t];
        const float em = __expf(-m);
        const float dt = den[nt] * em;
        const float denf = fmaxf(fabsf(dt), em) + B_EPS;
        const float inv = em / denf;
        float ssq = 0.f;
        #pragma unroll
        for (int mt = 0; mt < 8; ++mt) {
            #pragma unroll
            for (int i = 0; i < 4; ++i) {
                acc[nt][mt][i] *= inv;
                ssq += acc[nt][mt][i] * acc[nt][mt][i];
            }
        }
        ssq += __shfl_xor(ssq, 16);
        ssq += __shfl_xor(ssq, 32);
        const float rms = rsqrtf(ssq * (1.0f / DHH) + N_EPS);

        float* orow = out + ((size_t)b * SS + t) * DIMM + h * DHH;
        #pragma unroll
        for (int mt = 0; mt < 8; ++mt) {
            float4 gn = *(const float4*)&onw[h * DHH + mt * 16 + g * 4];
            float4 o4;
            o4.x = acc[nt][mt][0] * rms * (1.f + gn.x);
            o4.y = acc[nt][mt][1] * rms * (1.f + gn.y);
            o4.z = acc[nt][mt][2] * rms * (1.f + gn.z);
            o4.w = acc[nt][mt][3] * rms * (1.f + gn.w);
            *(float4*)&orow[mt * 16 + g * 4] = o4;
        }
    }
}

extern "C" void kernel_launch(void* const* d_in, const int* in_sizes, int n_in,
                              void* d_out, int out_size, void* d_ws, size_t ws_size,
                              hipStream_t stream) {
    const float* q   = (const float*)d_in[0];
    const float* k   = (const float*)d_in[1];
    const float* v   = (const float*)d_in[2];
    const float* gw  = (const float*)d_in[3];
    const float* gb  = (const float*)d_in[4];
    const float* onw = (const float*)d_in[5];
    float* out = (float*)d_out;

    float* ws    = (float*)d_ws;
    float* i_pre = ws;                  // 32768 f32
    float* lfcs  = ws + 32768;          // 32768
    float* mm    = ws + 65536;          // 32768
    float* aa    = ws + 98304;          // 32768 (pre-scaled by log2 e)
    float* pden  = ws + 131072;         // 480*128 f32
    unsigned short* pnum = (unsigned short*)((char*)d_ws + 1048576);   // 15728640 B
    unsigned short* k16  = (unsigned short*)((char*)d_ws + 16777216);  // 8388608 B
    unsigned short* v16  = (unsigned short*)((char*)d_ws + 25165824);  // 8388608 B

    hipLaunchKernelGGL(gate_kernel, dim3(BB * SS / 8), dim3(256), 0, stream,
                       q, k, v, gw, gb, i_pre, lfcs);
    hipLaunchKernelGGL(prep_scan, dim3(528), dim3(256), 0, stream,
                       k, v, k16, v16, i_pre, lfcs, mm, aa);
    hipLaunchKernelGGL(mlstm_splitk, dim3(480), dim3(256), 0, stream,
                       q, k16, v16, lfcs, aa, pnum, pden);
    hipLaunchKernelGGL(reduce_kernel, dim3(16 * 16), dim3(256), 0, stream,
                       pnum, pden, mm, onw, out);
}

// Round 9
// 76.497 us; speedup vs baseline: 27.2241x; 1.0503x over previous
//
#include <hip/hip_runtime.h>
#include <math.h>

#define BB 2
#define SS 2048
#define DIMM 1024
#define NHH 8
#define DHH 128
#define NSLOT 51   // 6-tile chunks, single-qq, per bh

constexpr float GATE_CAP = 15.0f;
constexpr float B_EPS = 5e-5f;
constexpr float N_EPS = 1e-6f;
constexpr float LOG2E = 1.4426950408889634f;
constexpr float LN_KIS = -2.4260151319598084f;   // ln(1/sqrt(128))

typedef _Float16 f16x8 __attribute__((ext_vector_type(8)));
typedef __fp16  h16x2 __attribute__((ext_vector_type(2)));
typedef float f32x4 __attribute__((ext_vector_type(4)));

union U8 { f16x8 v; h16x2 h[4]; unsigned int u[4]; };

// slot tables: descending qq (long chunks dispatch first), chunk ascending within qq
__device__ __constant__ unsigned char SLOT2QQ[NSLOT] = {
    15,15,15,15,15,15, 14,14,14,14,14, 13,13,13,13,13, 12,12,12,12,12,
    11,11,11,11, 10,10,10,10, 9,9,9,9, 8,8,8, 7,7,7, 6,6,6,
    5,5, 4,4, 3,3, 2, 1, 0};
__device__ __constant__ unsigned char SLOT2CH[NSLOT] = {
    0,1,2,3,4,5, 0,1,2,3,4, 0,1,2,3,4, 0,1,2,3,4,
    0,1,2,3, 0,1,2,3, 0,1,2,3, 0,1,2, 0,1,2, 0,1,2,
    0,1, 0,1, 0,1, 0, 0, 0};
__device__ __constant__ unsigned char QQ2BASE[16] = {50,49,48,46,44,42,39,36,33,29,25,21,16,11,6,0};
__device__ __constant__ unsigned char QQ2NCH[16]  = {1,1,1,2,2,2,3,3,3,4,4,4,5,5,5,6};

__device__ inline unsigned short f2bf(float x) {
    unsigned u = __builtin_bit_cast(unsigned, x);
    unsigned r = (u + 0x7fff + ((u >> 16) & 1)) >> 16;   // RTNE
    return (unsigned short)r;
}
__device__ inline float bf2f(unsigned short s) {
    unsigned u = ((unsigned)s) << 16;
    return __builtin_bit_cast(float, u);
}

#define GLD_LDS16(gsrc, ldst)                                                   \
    __builtin_amdgcn_global_load_lds(                                           \
        (const __attribute__((address_space(1))) unsigned int*)(gsrc),          \
        (__attribute__((address_space(3))) unsigned int*)(ldst), 16, 0, 0)

// ---------------- Kernel 1: gate GEMV + k16 emit from staged LDS ----------------
__global__ __launch_bounds__(256) void gate_kernel(
    const float* __restrict__ q, const float* __restrict__ k, const float* __restrict__ v,
    const float* __restrict__ gw, const float* __restrict__ gb,
    float* __restrict__ i_pre, float* __restrict__ lfcs,
    unsigned short* __restrict__ k16)
{
    __shared__ __align__(16) float xs[2][8][1024];

    const int tid = threadIdx.x;
    const int lane = tid & 63;
    const int wv = tid >> 6;
    const int bs0 = blockIdx.x * 8;

    const float* srcs[3] = {q, k, v};

    auto stage = [&](int buf, int i) {
        const char* src = (const char*)(srcs[i] + (size_t)bs0 * DIMM);
        #pragma unroll
        for (int j = 0; j < 8; ++j) {
            GLD_LDS16(src + j * 4096 + wv * 1024 + lane * 16,
                      (char*)&xs[buf][j][0] + wv * 1024 + lane * 16);
        }
    };

    float acc[8][4];
    #pragma unroll
    for (int r = 0; r < 8; ++r)
        #pragma unroll
        for (int o = 0; o < 4; ++o) acc[r][o] = 0.f;

    stage(0, 0);

    for (int i = 0; i < 3; ++i) {
        const int cur = i & 1;
        const float* gwi = gw + (wv * 4) * 3 * DIMM + i * DIMM;
        float4 w4[4][4];
        #pragma unroll
        for (int step = 0; step < 4; ++step)
            #pragma unroll
            for (int o = 0; o < 4; ++o)
                w4[step][o] = *(const float4*)&gwi[o * 3 * DIMM + step * 256 + lane * 4];

        if (i < 2) {
            stage(cur ^ 1, i + 1);
            asm volatile("s_waitcnt vmcnt(8)" ::: "memory");
        } else {
            asm volatile("s_waitcnt vmcnt(0)" ::: "memory");
        }
        __builtin_amdgcn_s_barrier();
        __builtin_amdgcn_sched_barrier(0);

        #pragma unroll
        for (int step = 0; step < 4; ++step) {
            #pragma unroll
            for (int r = 0; r < 8; ++r) {
                const float4 xv = *(const float4*)&xs[cur][r][step * 256 + lane * 4];
                #pragma unroll
                for (int o = 0; o < 4; ++o)
                    acc[r][o] += xv.x * w4[step][o].x + xv.y * w4[step][o].y
                               + xv.z * w4[step][o].z + xv.w * w4[step][o].w;
            }
        }
        __builtin_amdgcn_s_barrier();
    }

    // ---- k16 emit: k slice is resident in xs[1] ----
    #pragma unroll
    for (int it = 0; it < 8; ++it) {
        const int item = it * 256 + tid;      // 0..2047: 8 rows x 256 dq-groups
        const int r = item >> 8;
        const int dq = item & 255;            // 4-elem group within 1024 dims
        const int hh = dq >> 5;
        const int dd4 = dq & 31;
        float4 kx = *(const float4*)&xs[1][r][dq * 4];
        h16x2 p0 = __builtin_amdgcn_cvt_pkrtz(kx.x, kx.y);
        h16x2 p1 = __builtin_amdgcn_cvt_pkrtz(kx.z, kx.w);
        uint2 wd;
        wd.x = __builtin_bit_cast(unsigned int, p0);
        wd.y = __builtin_bit_cast(unsigned int, p1);
        const int bs = bs0 + r;
        const int b = bs >> 11, s2 = bs & 2047;
        const size_t bh = (size_t)b * NHH + hh;
        *(uint2*)((char*)k16 + (bh * 2048 + s2) * 256 + ((dd4 * 8) ^ ((s2 & 7) << 4))) = wd;
    }

    #pragma unroll
    for (int r = 0; r < 8; ++r)
        #pragma unroll
        for (int o = 0; o < 4; ++o) {
            acc[r][o] += __shfl_xor(acc[r][o], 16);
            acc[r][o] += __shfl_xor(acc[r][o], 32);
        }

    float* scr = &xs[0][0][0];
    const int l16 = lane & 15;
    if (l16 == lane) {
        #pragma unroll
        for (int r = 0; r < 8; ++r) {
            float4 st = {acc[r][0], acc[r][1], acc[r][2], acc[r][3]};
            *(float4*)&scr[wv * 576 + l16 * 36 + r * 4] = st;
        }
    }
    __syncthreads();

    if (tid < 128) {
        const int row = tid & 7, o = tid >> 3;
        const float* base = &scr[(o >> 2) * 576 + row * 4 + (o & 3)];
        float s = 0.f;
        #pragma unroll
        for (int j = 0; j < 16; ++j) s += base[j * 36];
        float p = s + gb[o];
        p = GATE_CAP * tanhf(p / GATE_CAP);
        const int bs = bs0 + row;
        const int b = bs >> 11, s2 = bs & 2047;
        if (o < NHH) {
            i_pre[((size_t)b * NHH + o) * SS + s2] = p;
        } else {
            const int h = o - NHH;
            const float ls = (p >= 0.f) ? -log1pf(expf(-p)) : p - log1pf(expf(p));
            lfcs[((size_t)b * NHH + h) * SS + s2] = ls;
        }
    }
}

// ---------------- Kernel 2: V transpose (blocks 0..511) + scan (512..527) ----------------
__global__ __launch_bounds__(256) void vscan_kernel(
    const float* __restrict__ v, unsigned short* __restrict__ v16,
    const float* __restrict__ i_pre,
    float* __restrict__ lfcs, float* __restrict__ mstab, float* __restrict__ aa)
{
    const int id = blockIdx.x;
    const int tid = threadIdx.x;
    __shared__ float wt[4], wm[4];

    if (id < 512) {
        const int bh = id & 15;
        const int st = id >> 4;
        const int b = bh >> 3, h = bh & 7;
        const int d2 = (tid & 63) * 2;
        const int kb = (tid >> 6) & 1;
        const int gq = tid >> 7;
        const float* vp = v + ((size_t)b * SS + st * 64 + kb * 32) * DIMM + h * DHH + d2;
        char* base = (char*)v16 + ((size_t)bh * 32 + st) * 16384;
        #pragma unroll
        for (int gg = 0; gg < 2; ++gg) {
            const int g = gq * 2 + gg;
            float2 e[8];
            #pragma unroll
            for (int j = 0; j < 8; ++j) {
                const int s = 16 * (j >> 2) + 4 * g + (j & 3);
                e[j] = *(const float2*)&vp[(size_t)s * DIMM];
            }
            U8 u0, u1;
            u0.h[0] = __builtin_amdgcn_cvt_pkrtz(e[0].x, e[1].x);
            u0.h[1] = __builtin_amdgcn_cvt_pkrtz(e[2].x, e[3].x);
            u0.h[2] = __builtin_amdgcn_cvt_pkrtz(e[4].x, e[5].x);
            u0.h[3] = __builtin_amdgcn_cvt_pkrtz(e[6].x, e[7].x);
            u1.h[0] = __builtin_amdgcn_cvt_pkrtz(e[0].y, e[1].y);
            u1.h[1] = __builtin_amdgcn_cvt_pkrtz(e[2].y, e[3].y);
            u1.h[2] = __builtin_amdgcn_cvt_pkrtz(e[4].y, e[5].y);
            u1.h[3] = __builtin_amdgcn_cvt_pkrtz(e[6].y, e[7].y);
            const int p0 = kb * 64 + g * 16;
            *(f16x8*)(base + d2 * 128       + (p0 ^ ((d2 & 7) << 4)))       = u0.v;
            *(f16x8*)(base + (d2 + 1) * 128 + (p0 ^ (((d2 + 1) & 7) << 4))) = u1.v;
        }
        return;
    }

    // ---- scan role ----
    const int bh = id - 512;
    const int lane = tid & 63, wv = tid >> 6;
    const size_t base = (size_t)bh * SS + tid * 8;

    float x[8];
    {
        float4 a0 = *(const float4*)&lfcs[base];
        float4 a1 = *(const float4*)&lfcs[base + 4];
        x[0] = a0.x; x[1] = a0.y; x[2] = a0.z; x[3] = a0.w;
        x[4] = a1.x; x[5] = a1.y; x[6] = a1.z; x[7] = a1.w;
    }
    #pragma unroll
    for (int i = 1; i < 8; ++i) x[i] += x[i - 1];

    const float tot = x[7];
    float inc = tot;
    #pragma unroll
    for (int off = 1; off < 64; off <<= 1) {
        float n = __shfl_up(inc, off);
        if (lane >= off) inc += n;
    }
    const float exc = inc - tot;

    if (lane == 63) wt[wv] = inc;
    __syncthreads();
    float wpre = 0.f;
    for (int w = 0; w < 4; ++w) if (w < wv) wpre += wt[w];
    const float off0 = exc + wpre;
    #pragma unroll
    for (int i = 0; i < 8; ++i) x[i] += off0;
    {
        float4 s0 = {x[0], x[1], x[2], x[3]}, s1 = {x[4], x[5], x[6], x[7]};
        *(float4*)&lfcs[base] = s0;
        *(float4*)&lfcs[base + 4] = s1;
    }

    float g[8];
    {
        float4 i0 = *(const float4*)&i_pre[base];
        float4 i1 = *(const float4*)&i_pre[base + 4];
        g[0] = i0.x - x[0]; g[1] = i0.y - x[1]; g[2] = i0.z - x[2]; g[3] = i0.w - x[3];
        g[4] = i1.x - x[4]; g[5] = i1.y - x[5]; g[6] = i1.z - x[6]; g[7] = i1.w - x[7];
        float4 s0 = {g[0] * LOG2E, g[1] * LOG2E, g[2] * LOG2E, g[3] * LOG2E};
        float4 s1 = {g[4] * LOG2E, g[5] * LOG2E, g[6] * LOG2E, g[7] * LOG2E};
        *(float4*)&aa[base] = s0;
        *(float4*)&aa[base + 4] = s1;
    }
    float mg[8];
    mg[0] = g[0];
    #pragma unroll
    for (int i = 1; i < 8; ++i) mg[i] = fmaxf(mg[i - 1], g[i]);

    float minc = mg[7];
    #pragma unroll
    for (int off = 1; off < 64; off <<= 1) {
        float n = __shfl_up(minc, off);
        if (lane >= off) minc = fmaxf(minc, n);
    }
    float mexc = __shfl_up(minc, 1);
    if (lane == 0) mexc = -1e30f;
    if (lane == 63) wm[wv] = minc;
    __syncthreads();
    float wmpre = -1e30f;
    for (int w = 0; w < 4; ++w) if (w < wv) wmpre = fmaxf(wmpre, wm[w]);
    const float pm = fmaxf(mexc, wmpre);
    float4 s0, s1;
    s0.x = x[0] + fmaxf(pm, mg[0]); s0.y = x[1] + fmaxf(pm, mg[1]);
    s0.z = x[2] + fmaxf(pm, mg[2]); s0.w = x[3] + fmaxf(pm, mg[3]);
    s1.x = x[4] + fmaxf(pm, mg[4]); s1.y = x[5] + fmaxf(pm, mg[5]);
    s1.z = x[6] + fmaxf(pm, mg[6]); s1.w = x[7] + fmaxf(pm, mg[7]);
    *(float4*)&mstab[base] = s0;
    *(float4*)&mstab[base + 4] = s1;
}

// ---------------- Kernel 3: MFMA mLSTM split-K, 816 balanced blocks ----------------
__global__ __launch_bounds__(256, 2) void mlstm_splitk(
    const float* __restrict__ q,
    const unsigned short* __restrict__ k16, const unsigned short* __restrict__ v16,
    const float* __restrict__ lfcs, const float* __restrict__ aa,
    unsigned short* __restrict__ pnum, float* __restrict__ pden)
{
    __shared__ __align__(16) unsigned short kbuf[2][8192];
    __shared__ __align__(16) unsigned short vbuf[2][8192];

    const int tid = threadIdx.x;
    const int lane = tid & 63;
    const int wv = tid >> 6;
    const int g = lane >> 4;
    const int l16 = lane & 15;

    const int id = blockIdx.x;
    const int bh = id & 15;
    const int slot = id >> 4;           // 0..50
    const int qq = SLOT2QQ[slot];
    const int chunk = SLOT2CH[slot];
    const int b = bh >> 3, h = bh & 7;
    const int tw0 = qq * 128 + 32 * wv;

    const size_t bhS = (size_t)bh * SS;
    const float* qp = q + (size_t)b * SS * DIMM + h * DHH;
    const char* kg = (const char*)k16 + (size_t)bh * 524288;
    const char* vg = (const char*)v16 + (size_t)bh * 524288;

    f16x8 qf[2][4];
    float cdec2[2];
    #pragma unroll
    for (int nt = 0; nt < 2; ++nt) {
        const int t = tw0 + 16 * nt + l16;
        cdec2[nt] = (lfcs[bhS + t] + LN_KIS) * LOG2E;
        const float* qrow = qp + (size_t)t * DIMM;
        #pragma unroll
        for (int kb = 0; kb < 4; ++kb) {
            float4 x0 = *(const float4*)&qrow[kb * 32 + g * 8];
            float4 x1 = *(const float4*)&qrow[kb * 32 + g * 8 + 4];
            U8 uu;
            uu.h[0] = __builtin_amdgcn_cvt_pkrtz(x0.x, x0.y);
            uu.h[1] = __builtin_amdgcn_cvt_pkrtz(x0.z, x0.w);
            uu.h[2] = __builtin_amdgcn_cvt_pkrtz(x1.x, x1.y);
            uu.h[3] = __builtin_amdgcn_cvt_pkrtz(x1.z, x1.w);
            qf[nt][kb] = uu.v;
        }
    }

    f32x4 oacc[2][8];
    #pragma unroll
    for (int nt = 0; nt < 2; ++nt)
        #pragma unroll
        for (int mt = 0; mt < 8; ++mt)
            oacc[nt][mt] = (f32x4){0.f, 0.f, 0.f, 0.f};
    float dpart[2] = {0.f, 0.f};

    const int st0 = chunk * 6;
    const int st1m = 2 * qq + 1;
    const int st1 = (st0 + 5 < st1m) ? (st0 + 5) : st1m;

    auto stage = [&](int bi, int st) {
        const char* ksrc = kg + (size_t)st * 16384;
        const char* vsrc = vg + (size_t)st * 16384;
        #pragma unroll
        for (int j = 0; j < 4; ++j) {
            const int off = (j * 4 + wv) * 1024;
            GLD_LDS16(ksrc + off + lane * 16, (char*)&kbuf[bi][0] + off);
            GLD_LDS16(vsrc + off + lane * 16, (char*)&vbuf[bi][0] + off);
        }
    };

    stage(0, st0);

    for (int st = st0; st <= st1; ++st) {
        const int cur = (st - st0) & 1;
        const float* ap = aa + bhS + st * 64;
        f32x4 av[4];
        av[0] = *(const f32x4*)&ap[g * 4];
        av[1] = *(const f32x4*)&ap[16 + g * 4];
        av[2] = *(const f32x4*)&ap[32 + g * 4];
        av[3] = *(const f32x4*)&ap[48 + g * 4];

        if (st < st1) {
            stage(cur ^ 1, st + 1);
            asm volatile("s_waitcnt vmcnt(8)" ::: "memory");
        } else {
            asm volatile("s_waitcnt vmcnt(0)" ::: "memory");
        }
        __builtin_amdgcn_s_barrier();
        __builtin_amdgcn_sched_barrier(0);

        const int s0 = st * 64;
        const bool diag = (st >= 2 * qq);

        f32x4 stacc[2][4];
        #pragma unroll
        for (int nt = 0; nt < 2; ++nt)
            #pragma unroll
            for (int ct = 0; ct < 4; ++ct)
                stacc[nt][ct] = (f32x4){0.f, 0.f, 0.f, 0.f};

        f16x8 pf[2][2];

        #define QKT_PAIR(CT0)                                                            \
            __builtin_amdgcn_s_setprio(1);                                               \
            _Pragma("unroll")                                                            \
            for (int ct = CT0; ct < CT0 + 2; ++ct) {                                     \
                const int row = ct * 16 + l16;                                           \
                _Pragma("unroll")                                                        \
                for (int kb = 0; kb < 4; ++kb) {                                         \
                    f16x8 kf = *(const f16x8*)((const char*)&kbuf[cur][0] +              \
                                ((row * 256 + kb * 64 + g * 16) ^ ((row & 7) << 4)));    \
                    stacc[0][ct] = __builtin_amdgcn_mfma_f32_16x16x32_f16(kf, qf[0][kb], stacc[0][ct], 0, 0, 0); \
                    stacc[1][ct] = __builtin_amdgcn_mfma_f32_16x16x32_f16(kf, qf[1][kb], stacc[1][ct], 0, 0, 0); \
                }                                                                        \
            }                                                                            \
            __builtin_amdgcn_s_setprio(0);

        #define DECAY_PACK(KB)                                                           \
            _Pragma("unroll")                                                            \
            for (int nt = 0; nt < 2; ++nt) {                                             \
                float dsum = 0.f;                                                        \
                const int t_idx = tw0 + nt * 16 + l16;                                   \
                _Pragma("unroll")                                                        \
                for (int ct = 2 * (KB); ct < 2 * (KB) + 2; ++ct) {                       \
                    _Pragma("unroll")                                                    \
                    for (int i = 0; i < 4; ++i) {                                        \
                        const float e = __builtin_amdgcn_exp2f(cdec2[nt] + av[ct][i]);   \
                        float val = stacc[nt][ct][i] * e;                                \
                        if (diag && (s0 + ct * 16 + g * 4 + i > t_idx)) val = 0.f;       \
                        dsum += val;                                                     \
                        stacc[nt][ct][i] = val;                                          \
                    }                                                                    \
                }                                                                        \
                dpart[nt] += dsum;                                                       \
                U8 uu;                                                                   \
                uu.h[0] = __builtin_amdgcn_cvt_pkrtz(stacc[nt][2*(KB)][0],   stacc[nt][2*(KB)][1]);   \
                uu.h[1] = __builtin_amdgcn_cvt_pkrtz(stacc[nt][2*(KB)][2],   stacc[nt][2*(KB)][3]);   \
                uu.h[2] = __builtin_amdgcn_cvt_pkrtz(stacc[nt][2*(KB)+1][0], stacc[nt][2*(KB)+1][1]); \
                uu.h[3] = __builtin_amdgcn_cvt_pkrtz(stacc[nt][2*(KB)+1][2], stacc[nt][2*(KB)+1][3]); \
                pf[nt][KB] = uu.v;                                                       \
            }

        #define PV_HALF(KB)                                                              \
            __builtin_amdgcn_s_setprio(1);                                               \
            _Pragma("unroll")                                                            \
            for (int mt = 0; mt < 8; ++mt) {                                             \
                const int dI = mt * 16 + l16;                                            \
                f16x8 vf = *(const f16x8*)((const char*)&vbuf[cur][0] +                  \
                            dI * 128 + (((KB) * 64 + g * 16) ^ ((dI & 7) << 4)));        \
                oacc[0][mt] = __builtin_amdgcn_mfma_f32_16x16x32_f16(vf, pf[0][KB], oacc[0][mt], 0, 0, 0); \
                oacc[1][mt] = __builtin_amdgcn_mfma_f32_16x16x32_f16(vf, pf[1][KB], oacc[1][mt], 0, 0, 0); \
            }                                                                            \
            __builtin_amdgcn_s_setprio(0);

        QKT_PAIR(0)
        DECAY_PACK(0)
        QKT_PAIR(2)
        PV_HALF(0)
        DECAY_PACK(1)
        PV_HALF(1)

        #undef QKT_PAIR
        #undef DECAY_PACK
        #undef PV_HALF

        __builtin_amdgcn_sched_barrier(0);
        __builtin_amdgcn_s_barrier();
    }

    const size_t cidx = (size_t)bh * NSLOT + slot;
    #pragma unroll
    for (int nt = 0; nt < 2; ++nt) {
        float den = dpart[nt];
        den += __shfl_xor(den, 16);
        den += __shfl_xor(den, 32);
        const int row = wv * 32 + nt * 16 + l16;
        if (g == 0) pden[cidx * 128 + row] = den;
        #pragma unroll
        for (int mt = 0; mt < 8; ++mt) {
            ushort4 pk;
            pk.x = f2bf(oacc[nt][mt][0]);
            pk.y = f2bf(oacc[nt][mt][1]);
            pk.z = f2bf(oacc[nt][mt][2]);
            pk.w = f2bf(oacc[nt][mt][3]);
            *(ushort4*)&pnum[((cidx * 64 + wv * 16 + nt * 8 + mt) << 8) + lane * 4] = pk;
        }
    }
}

// ---------------- Kernel 4: chunk reduction + denom + RMSNorm ----------------
__global__ __launch_bounds__(256) void reduce_kernel(
    const unsigned short* __restrict__ pnum, const float* __restrict__ pden,
    const float* __restrict__ mstab, const float* __restrict__ onw,
    float* __restrict__ out)
{
    const int id = blockIdx.x;
    const int bh = id & 15;
    const int qq = id >> 4;
    const int b = bh >> 3, h = bh & 7;
    const int tid = threadIdx.x;
    const int lane = tid & 63;
    const int wv = tid >> 6;
    const int g = lane >> 4;
    const int l16 = lane & 15;

    const int nch = QQ2NCH[qq];
    const size_t cbase = (size_t)bh * NSLOT + QQ2BASE[qq];

    f32x4 acc[2][8];
    #pragma unroll
    for (int nt = 0; nt < 2; ++nt)
        #pragma unroll
        for (int mt = 0; mt < 8; ++mt)
            acc[nt][mt] = (f32x4){0.f, 0.f, 0.f, 0.f};
    float den[2] = {0.f, 0.f};

    for (int c = 0; c < nch; ++c) {
        const size_t fb = (cbase + c) * 64 + wv * 16;
        #pragma unroll
        for (int nt = 0; nt < 2; ++nt) {
            #pragma unroll
            for (int mt = 0; mt < 8; ++mt) {
                ushort4 t4 = *(const ushort4*)&pnum[((fb + nt * 8 + mt) << 8) + lane * 4];
                acc[nt][mt][0] += bf2f(t4.x);
                acc[nt][mt][1] += bf2f(t4.y);
                acc[nt][mt][2] += bf2f(t4.z);
                acc[nt][mt][3] += bf2f(t4.w);
            }
            den[nt] += pden[(cbase + c) * 128 + wv * 32 + nt * 16 + l16];
        }
    }

    #pragma unroll
    for (int nt = 0; nt < 2; ++nt) {
        const int t = qq * 128 + wv * 32 + nt * 16 + l16;
        const float m = mstab[(size_t)bh * SS + t];
        const float em = __expf(-m);
        const float dt = den[nt] * em;
        const float denf = fmaxf(fabsf(dt), em) + B_EPS;
        const float inv = em / denf;
        float ssq = 0.f;
        #pragma unroll
        for (int mt = 0; mt < 8; ++mt) {
            #pragma unroll
            for (int i = 0; i < 4; ++i) {
                acc[nt][mt][i] *= inv;
                ssq += acc[nt][mt][i] * acc[nt][mt][i];
            }
        }
        ssq += __shfl_xor(ssq, 16);
        ssq += __shfl_xor(ssq, 32);
        const float rms = rsqrtf(ssq * (1.0f / DHH) + N_EPS);

        float* orow = out + ((size_t)b * SS + t) * DIMM + h * DHH;
        #pragma unroll
        for (int mt = 0; mt < 8; ++mt) {
            float4 gn = *(const float4*)&onw[h * DHH + mt * 16 + g * 4];
            float4 o4;
            o4.x = acc[nt][mt][0] * rms * (1.f + gn.x);
            o4.y = acc[nt][mt][1] * rms * (1.f + gn.y);
            o4.z = acc[nt][mt][2] * rms * (1.f + gn.z);
            o4.w = acc[nt][mt][3] * rms * (1.f + gn.w);
            *(float4*)&orow[mt * 16 + g * 4] = o4;
        }
    }
}

extern "C" void kernel_launch(void* const* d_in, const int* in_sizes, int n_in,
                              void* d_out, int out_size, void* d_ws, size_t ws_size,
                              hipStream_t stream) {
    const float* q   = (const float*)d_in[0];
    const float* k   = (const float*)d_in[1];
    const float* v   = (const float*)d_in[2];
    const float* gw  = (const float*)d_in[3];
    const float* gb  = (const float*)d_in[4];
    const float* onw = (const float*)d_in[5];
    float* out = (float*)d_out;

    float* ws    = (float*)d_ws;
    float* i_pre = ws;                  // 32768 f32
    float* lfcs  = ws + 32768;          // 32768
    float* mm    = ws + 65536;          // 32768
    float* aa    = ws + 98304;          // 32768 (pre-scaled by log2 e)
    float* pden  = ws + 131072;         // 816*128 f32 = 104448 (ends < 262144)
    unsigned short* pnum = (unsigned short*)((char*)d_ws + 1048576);   // 816*32KB = 26738688 B
    unsigned short* k16  = (unsigned short*)((char*)d_ws + 29360128);  // 8388608 B
    unsigned short* v16  = (unsigned short*)((char*)d_ws + 37748736);  // 8388608 B -> end ~46 MB

    hipLaunchKernelGGL(gate_kernel, dim3(BB * SS / 8), dim3(256), 0, stream,
                       q, k, v, gw, gb, i_pre, lfcs, k16);
    hipLaunchKernelGGL(vscan_kernel, dim3(528), dim3(256), 0, stream,
                       v, v16, i_pre, lfcs, mm, aa);
    hipLaunchKernelGGL(mlstm_splitk, dim3(16 * NSLOT), dim3(256), 0, stream,
                       q, k16, v16, lfcs, aa, pnum, pden);
    hipLaunchKernelGGL(reduce_kernel, dim3(16 * 16), dim3(256), 0, stream,
                       pnum, pden, mm, onw, out);
}